// Round 1
// baseline (1146.090 us; speedup 1.0000x reference)
//
#include <hip/hip_runtime.h>
#include <math.h>

#define BB 2
#define NN_ 4096
#define DIM 512
#define NH 8
#define DH 64
#define FF 256
#define CH 128
#define NC 32              // chunks per (b,h)
#define NROWS (BB*NN_)     // 8192
#define NBH (BB*NH)        // 16
#define NCHUNK (NBH*NC)    // 512

// ---------------- generic f32 tiled GEMM: C = scale * A @ W^T (+bias) ----------------
// A[m][k] at A + z*zA + m*lda + k ; W[n][k] at W + n*ldb + k ; C at C + z*zC + m*ldc + n
template<bool HAS_BIAS>
__global__ __launch_bounds__(256)
void gemm_nt(const float* __restrict__ A, int lda, int zA,
             const float* __restrict__ W, int ldb,
             float* __restrict__ C, int ldc, int zC,
             const float* __restrict__ bias, int K, float scale)
{
    const int m0 = blockIdx.x * 64;
    const int n0 = blockIdx.y * 64;
    A += (size_t)blockIdx.z * zA;
    C += (size_t)blockIdx.z * zC;
    __shared__ float As[64][36];
    __shared__ float Ws[64][36];
    const int tid = threadIdx.x;
    const int ty = tid >> 4, tx = tid & 15;
    float acc[4][4] = {};
    for (int k0 = 0; k0 < K; k0 += 32) {
        for (int t = tid; t < 512; t += 256) {
            int i = t >> 3, kq = (t & 7) * 4;
            *(float4*)&As[i][kq] = *(const float4*)&A[(size_t)(m0 + i) * lda + k0 + kq];
            *(float4*)&Ws[i][kq] = *(const float4*)&W[(size_t)(n0 + i) * ldb + k0 + kq];
        }
        __syncthreads();
        #pragma unroll
        for (int kb = 0; kb < 8; kb++) {
            float4 av[4], wv[4];
            #pragma unroll
            for (int r = 0; r < 4; r++) av[r] = *(float4*)&As[ty + 16*r][kb*4];
            #pragma unroll
            for (int c = 0; c < 4; c++) wv[c] = *(float4*)&Ws[tx + 16*c][kb*4];
            #pragma unroll
            for (int r = 0; r < 4; r++)
                #pragma unroll
                for (int c = 0; c < 4; c++)
                    acc[r][c] += av[r].x*wv[c].x + av[r].y*wv[c].y
                               + av[r].z*wv[c].z + av[r].w*wv[c].w;
        }
        __syncthreads();
    }
    #pragma unroll
    for (int r = 0; r < 4; r++) {
        int m = m0 + ty + 16*r;
        #pragma unroll
        for (int c = 0; c < 4; c++) {
            int n = n0 + tx + 16*c;
            float v = scale * acc[r][c];
            if (HAS_BIAS) v += bias[n];
            C[(size_t)m * ldc + n] = v;
        }
    }
}

// ---------------- wave helpers ----------------
__device__ inline float wave_max(float v) {
    #pragma unroll
    for (int off = 32; off; off >>= 1) v = fmaxf(v, __shfl_xor(v, off));
    return v;
}
__device__ inline float wave_sum(float v) {
    #pragma unroll
    for (int off = 32; off; off >>= 1) v += __shfl_xor(v, off);
    return v;
}

// ---------------- global max over dd_k (ordered-uint key) ----------------
__global__ __launch_bounds__(256)
void gmax_reduce(const float* __restrict__ dd, unsigned* __restrict__ out)
{
    const size_t total4 = (size_t)NROWS * NH * FF / 4;
    size_t stride = (size_t)gridDim.x * 256;
    float lm = -1e30f;
    for (size_t p = (size_t)blockIdx.x * 256 + threadIdx.x; p < total4; p += stride) {
        float4 v = ((const float4*)dd)[p];
        lm = fmaxf(lm, fmaxf(fmaxf(v.x, v.y), fmaxf(v.z, v.w)));
    }
    lm = wave_max(lm);
    if ((threadIdx.x & 63) == 0) {
        unsigned u = __float_as_uint(lm);
        unsigned key = (u & 0x80000000u) ? ~u : (u | 0x80000000u);
        atomicMax(out, key);
    }
}

// ---------------- feature-map finalize: one wave per (row,h) ----------------
// dd [8192][2048] in place -> phi = ratio*(exp(dd - diag - m) + 1e-4)
__global__ __launch_bounds__(64)
void feat_finalize(float* __restrict__ dd, const float* __restrict__ lin,
                   const unsigned* __restrict__ gmaxkey, int is_query)
{
    const int blk = blockIdx.x;
    const int row = blk >> 3, h = blk & 7;
    const int lane = threadIdx.x;
    float q = lin[(size_t)row * DIM + h * DH + lane];
    float diag = 0.0625f * wave_sum(q * q);          // 0.5*dn^2*||q||^2
    float* p = dd + (size_t)row * (NH*FF) + h * FF;
    float4 v = *(float4*)&p[lane * 4];
    float m;
    if (is_query) {
        m = wave_max(fmaxf(fmaxf(v.x, v.y), fmaxf(v.z, v.w)));
    } else {
        unsigned key = *gmaxkey;
        unsigned ub = (key & 0x80000000u) ? (key & 0x7fffffffu) : ~key;
        m = __uint_as_float(ub);
    }
    float s = diag + m;
    v.x = 0.0625f * (expf(v.x - s) + 1e-4f);
    v.y = 0.0625f * (expf(v.y - s) + 1e-4f);
    v.z = 0.0625f * (expf(v.z - s) + 1e-4f);
    v.w = 0.0625f * (expf(v.w - s) + 1e-4f);
    *(float4*)&p[lane * 4] = v;
}

// ---------------- Pass A: per-chunk S = K^T V, Z = colsum(K) ----------------
__global__ __launch_bounds__(256)
void chunk_sums(const float* __restrict__ kp, const float* __restrict__ vlin,
                float* __restrict__ sbuf, float* __restrict__ zbuf)
{
    const int gc = blockIdx.x;
    const int c = gc & 31, bh = gc >> 5;
    const int b = bh >> 3, h = bh & 7;
    const int row0 = b * NN_ + c * CH;
    const int j = threadIdx.x;
    __shared__ float Vs[CH][DH];
    for (int t = threadIdx.x; t < CH*DH; t += 256) {
        int r = t >> 6, e = t & 63;
        Vs[r][e] = vlin[(size_t)(row0 + r) * DIM + h * DH + e];
    }
    __syncthreads();
    float acc[DH] = {};
    float z = 0.f;
    const float* kc = kp + (size_t)row0 * (NH*FF) + h * FF;
    for (int r = 0; r < CH; r++) {
        float kv = kc[(size_t)r * (NH*FF) + j];
        z += kv;
        #pragma unroll
        for (int e4 = 0; e4 < 16; e4++) {
            float4 vv = *(float4*)&Vs[r][e4*4];
            acc[e4*4+0] += kv * vv.x;  acc[e4*4+1] += kv * vv.y;
            acc[e4*4+2] += kv * vv.z;  acc[e4*4+3] += kv * vv.w;
        }
    }
    float* sp = sbuf + (size_t)gc * (FF*DH) + j * DH;
    #pragma unroll
    for (int e4 = 0; e4 < 16; e4++)
        *(float4*)&sp[e4*4] = make_float4(acc[e4*4], acc[e4*4+1], acc[e4*4+2], acc[e4*4+3]);
    zbuf[(size_t)gc * FF + j] = z;
}

// ---------------- Pass B: exclusive prefix over chunks; finals -> outputs ----------------
__global__ __launch_bounds__(256)
void prefix_states(float* __restrict__ sbuf, float* __restrict__ zbuf,
                   float* __restrict__ outZ, float* __restrict__ outS)
{
    const int bh = blockIdx.x;
    const int tid = threadIdx.x;
    float run[65];
    #pragma unroll
    for (int i = 0; i < 65; i++) run[i] = 0.f;
    for (int c = 0; c < NC; c++) {
        float* bs = sbuf + (size_t)(bh*NC + c) * (FF*DH);
        #pragma unroll 4
        for (int ii = 0; ii < 64; ii++) {
            int idx = tid + ii * 256;
            float v = bs[idx]; bs[idx] = run[ii]; run[ii] += v;
        }
        float* bz = zbuf + (size_t)(bh*NC + c) * FF + tid;
        float v = *bz; *bz = run[64]; run[64] += v;
    }
    for (int ii = 0; ii < 64; ii++)
        outS[(size_t)bh * (FF*DH) + tid + ii*256] = run[ii];
    outZ[(size_t)bh * FF + tid] = run[64];
}

// ---------------- Pass C: per-chunk output ----------------
__global__ __launch_bounds__(256)
void chunk_out(const float* __restrict__ qp, const float* __restrict__ kp,
               const float* __restrict__ vlin,
               const float* __restrict__ sbuf, const float* __restrict__ zbuf,
               float* __restrict__ aout)
{
    extern __shared__ float sm[];
    float* A_s = sm;                       // [128][129]
    float* Qs  = sm + 128*129;             // [128][68]   (V in phase 3)
    float* Ks  = Qs + 128*68;              // [128][68]   (S_prev tile in phase 1)
    float* Zps = Ks + 128*68;              // [64]
    const int gc = blockIdx.x;
    const int c = gc & 31, bh = gc >> 5;
    const int b = bh >> 3, h = bh & 7;
    const int row0 = b * NN_ + c * CH;
    const float* Qg = qp + (size_t)row0 * (NH*FF) + h * FF;
    const float* Kg = kp + (size_t)row0 * (NH*FF) + h * FF;
    const float* Sp = sbuf + (size_t)gc * (FF*DH);
    const float* Zp = zbuf + (size_t)gc * FF;
    const int tid = threadIdx.x;
    const int i1 = tid >> 1, e0 = (tid & 1) * 32;

    float out[32] = {};
    float D = 0.f, sumQ = 0.f;

    // phase 1: out += Q @ S_prev ; D += Q.Z_prev ; sumQ
    for (int f0 = 0; f0 < FF; f0 += 64) {
        for (int t = tid; t < 128*16; t += 256) {
            int i = t >> 4, fq = (t & 15) * 4;
            *(float4*)&Qs[i*68 + fq] = *(const float4*)&Qg[(size_t)i * (NH*FF) + f0 + fq];
        }
        for (int t = tid; t < 64*16; t += 256) {
            int fk = t >> 4, eq = (t & 15) * 4;
            *(float4*)&Ks[fk*68 + eq] = *(const float4*)&Sp[(size_t)(f0+fk) * DH + eq];
        }
        if (tid < 64) Zps[tid] = Zp[f0 + tid];
        __syncthreads();
        for (int fk = 0; fk < 64; fk++) {
            float qf = Qs[i1*68 + fk];
            D += qf * Zps[fk];
            sumQ += qf;
            #pragma unroll
            for (int e4 = 0; e4 < 8; e4++) {
                float4 sv = *(float4*)&Ks[fk*68 + e0 + e4*4];
                out[e4*4+0] += qf * sv.x;  out[e4*4+1] += qf * sv.y;
                out[e4*4+2] += qf * sv.z;  out[e4*4+3] += qf * sv.w;
            }
        }
        __syncthreads();
    }

    // phase 2: A = tril(Q K^T)
    {
        const int ty = tid >> 4, tx = tid & 15;
        float acc[8][8] = {};
        for (int f0 = 0; f0 < FF; f0 += 64) {
            for (int t = tid; t < 128*16; t += 256) {
                int i = t >> 4, fq = (t & 15) * 4;
                *(float4*)&Qs[i*68 + fq] = *(const float4*)&Qg[(size_t)i * (NH*FF) + f0 + fq];
                *(float4*)&Ks[i*68 + fq] = *(const float4*)&Kg[(size_t)i * (NH*FF) + f0 + fq];
            }
            __syncthreads();
            #pragma unroll
            for (int kb = 0; kb < 16; kb++) {
                float4 av[8], bv[8];
                #pragma unroll
                for (int r = 0; r < 8; r++) av[r] = *(float4*)&Qs[(ty + 16*r)*68 + kb*4];
                #pragma unroll
                for (int cc = 0; cc < 8; cc++) bv[cc] = *(float4*)&Ks[(tx + 16*cc)*68 + kb*4];
                #pragma unroll
                for (int r = 0; r < 8; r++)
                    #pragma unroll
                    for (int cc = 0; cc < 8; cc++)
                        acc[r][cc] += av[r].x*bv[cc].x + av[r].y*bv[cc].y
                                    + av[r].z*bv[cc].z + av[r].w*bv[cc].w;
            }
            __syncthreads();
        }
        #pragma unroll
        for (int r = 0; r < 8; r++) {
            int i = ty + 16*r;
            #pragma unroll
            for (int cc = 0; cc < 8; cc++) {
                int j = tx + 16*cc;
                A_s[i*129 + j] = (j <= i) ? acc[r][cc] : 0.f;
            }
        }
        __syncthreads();
    }

    // phase 3: out += tril(A) @ V ; D += rowsum(tril(A))
    {
        for (int t = tid; t < 128*16; t += 256) {
            int r = t >> 4, eq = (t & 15) * 4;
            *(float4*)&Qs[r*68 + eq] = *(const float4*)&vlin[(size_t)(row0 + r) * DIM + h * DH + eq];
        }
        __syncthreads();
        for (int j = 0; j < CH; j++) {
            float a = A_s[i1*129 + j];
            D += a;
            #pragma unroll
            for (int e4 = 0; e4 < 8; e4++) {
                float4 vv = *(float4*)&Qs[j*68 + e0 + e4*4];
                out[e4*4+0] += a * vv.x;  out[e4*4+1] += a * vv.y;
                out[e4*4+2] += a * vv.z;  out[e4*4+3] += a * vv.w;
            }
        }
    }
    float Dinv = 1.f / (D + 1e-6f * sumQ);
    float* op = aout + (size_t)(row0 + i1) * DIM + h * DH + e0;
    #pragma unroll
    for (int e4 = 0; e4 < 8; e4++) {
        float4 v = make_float4(out[e4*4]*Dinv, out[e4*4+1]*Dinv,
                               out[e4*4+2]*Dinv, out[e4*4+3]*Dinv);
        *(float4*)&op[e4*4] = v;
    }
}

extern "C" void kernel_launch(void* const* d_in, const int* in_sizes, int n_in,
                              void* d_out, int out_size, void* d_ws, size_t ws_size,
                              hipStream_t stream)
{
    const float* x    = (const float*)d_in[0];
    const float* Wq   = (const float*)d_in[1];
    const float* Wk   = (const float*)d_in[2];
    const float* Wv   = (const float*)d_in[3];
    const float* Wo   = (const float*)d_in[4];
    const float* bo   = (const float*)d_in[5];
    const float* proj = (const float*)d_in[6];
    float* out = (float*)d_out;

    float* ws   = (float*)d_ws;
    float* ddq  = ws;                      // 16,777,216  (-> qp in place)
    float* ddk  = ddq + 16777216;          // 16,777,216  (-> kp in place)
    float* qlin = ddk + 16777216;          // 4,194,304   (reused as attn-out)
    float* klin = qlin + 4194304;          // 4,194,304
    float* vlin = klin + 4194304;          // 4,194,304
    float* sbuf = vlin + 4194304;          // 8,388,608
    float* zbuf = sbuf + 8388608;          // 131,072
    unsigned* gmax = (unsigned*)(zbuf + 131072);
    float* aout = qlin;

    float* outO = out;                     // [2,4096,512]
    float* outZ = out + 4194304;           // [2,8,256]
    float* outS = outZ + 4096;             // [2,8,256,64]

    const float dn = 0.35355339059327373f; // 64^-0.25

    dim3 blk(256);
    // QKV projections
    gemm_nt<false><<<dim3(128, 8, 1), blk, 0, stream>>>(x, DIM, 0, Wq, DIM, qlin, DIM, 0, nullptr, DIM, 1.f);
    gemm_nt<false><<<dim3(128, 8, 1), blk, 0, stream>>>(x, DIM, 0, Wk, DIM, klin, DIM, 0, nullptr, DIM, 1.f);
    gemm_nt<false><<<dim3(128, 8, 1), blk, 0, stream>>>(x, DIM, 0, Wv, DIM, vlin, DIM, 0, nullptr, DIM, 1.f);
    // dd = dn * q_head @ proj^T  (blockIdx.z = head)
    gemm_nt<false><<<dim3(128, 4, 8), blk, 0, stream>>>(qlin, DIM, DH, proj, DH, ddq, NH*FF, FF, nullptr, DH, dn);
    gemm_nt<false><<<dim3(128, 4, 8), blk, 0, stream>>>(klin, DIM, DH, proj, DH, ddk, NH*FF, FF, nullptr, DH, dn);
    // global max over dd_k
    hipMemsetAsync(gmax, 0, 4, stream);
    gmax_reduce<<<2048, 256, 0, stream>>>(ddk, gmax);
    // feature-map finalize (in place)
    feat_finalize<<<NROWS*NH, 64, 0, stream>>>(ddq, qlin, nullptr, 1);
    feat_finalize<<<NROWS*NH, 64, 0, stream>>>(ddk, klin, gmax, 0);
    // chunked linear attention
    chunk_sums<<<NCHUNK, 256, 0, stream>>>(ddk, vlin, sbuf, zbuf);
    prefix_states<<<NBH, 256, 0, stream>>>(sbuf, zbuf, outZ, outS);
    size_t smC = (size_t)(128*129 + 128*68*2 + 64) * sizeof(float);
    hipFuncSetAttribute((const void*)chunk_out, hipFuncAttributeMaxDynamicSharedMemorySize, (int)smC);
    chunk_out<<<NCHUNK, 256, smC, stream>>>(ddq, ddk, vlin, sbuf, zbuf, aout);
    // output projection
    gemm_nt<true><<<dim3(128, 8, 1), blk, 0, stream>>>(aout, DIM, 0, Wo, DIM, outO, DIM, 0, bo, DIM, 1.f);
}

// Round 3
// 713.079 us; speedup vs baseline: 1.6072x; 1.6072x over previous
//
#include <hip/hip_runtime.h>

#define NH 8
#define DH 64
#define FF 256
#define CH 128

typedef unsigned short u16;
typedef unsigned int u32;
typedef __attribute__((ext_vector_type(8))) short bf16x8;
typedef __attribute__((ext_vector_type(4))) float f32x4;

__device__ __forceinline__ u16 f2bf(float f) {
    u32 u = __float_as_uint(f);
    return (u16)((u + 0x7fffu + ((u >> 16) & 1u)) >> 16);
}
__device__ __forceinline__ float bf2f(u16 h) { return __uint_as_float(((u32)h) << 16); }
__device__ __forceinline__ u32 pk(u16 a, u16 b) { return (u32)a | ((u32)b << 16); }
// XOR-swizzled byte offset for bf16 LDS tiles (ld = row elems, mult of 64)
__device__ __forceinline__ int swz(int row, int col, int ld) {
    return ((row * ld + col) * 2) ^ ((row & 7) << 4);
}
__device__ __forceinline__ f32x4 MF(bf16x8 a, bf16x8 b, f32x4 c) {
    return __builtin_amdgcn_mfma_f32_16x16x32_bf16(a, b, c, 0, 0, 0);
}
__device__ __forceinline__ float wave_max(float v) {
    #pragma unroll
    for (int o = 32; o; o >>= 1) v = fmaxf(v, __shfl_xor(v, o));
    return v;
}
__device__ __forceinline__ float wave_sum(float v) {
    #pragma unroll
    for (int o = 32; o; o >>= 1) v += __shfl_xor(v, o);
    return v;
}

// ---------- split-bf16 convert: A:[hi|hi|lo]  B:[hi|lo|hi] ----------
template<bool ISB>
__global__ __launch_bounds__(256)
void conv_split(const float* __restrict__ src, u16* __restrict__ dst,
                int K, long total4, float scale)
{
    const int K4 = K >> 2;
    for (long i = (long)blockIdx.x * 256 + threadIdx.x; i < total4;
         i += (long)gridDim.x * 256) {
        long row = i / K4;
        int c = (int)(i - row * K4) * 4;
        float4 v = ((const float4*)src)[i];
        float a0 = v.x * scale, a1 = v.y * scale, a2 = v.z * scale, a3 = v.w * scale;
        u16 h0 = f2bf(a0), h1 = f2bf(a1), h2 = f2bf(a2), h3 = f2bf(a3);
        u16 l0 = f2bf(a0 - bf2f(h0)), l1 = f2bf(a1 - bf2f(h1));
        u16 l2 = f2bf(a2 - bf2f(h2)), l3 = f2bf(a3 - bf2f(h3));
        uint2 hh; hh.x = pk(h0, h1); hh.y = pk(h2, h3);
        uint2 ll; ll.x = pk(l0, l1); ll.y = pk(l2, l3);
        u16* d = dst + row * (3L * K) + c;
        *(uint2*)d = hh;
        *(uint2*)(d + (ISB ? 2 * K : K)) = hh;
        *(uint2*)(d + (ISB ? K : 2 * K)) = ll;
    }
}

// ---------- bf16 MFMA NT GEMM: C = scale * A @ B^T (+bias). 128x128 tile, BK=64 ----------
template<bool HAS_BIAS>
__global__ __launch_bounds__(256, 2)
void gemm_mfma(const u16* __restrict__ A, int lda, int zA,
               const u16* __restrict__ B, int ldb, int zB,
               float* __restrict__ C, int ldc, int zC,
               const float* __restrict__ bias, int K, float scale)
{
    __shared__ char smem[32768];
    char* As = smem; char* Bs = smem + 16384;
    A += (size_t)blockIdx.z * zA; B += (size_t)blockIdx.z * zB; C += (size_t)blockIdx.z * zC;
    const int m0 = blockIdx.x * 128, n0 = blockIdx.y * 128;
    const int tid = threadIdx.x, lane = tid & 63, wave = tid >> 6;
    const int wm = (wave >> 1) * 64, wn = (wave & 1) * 64;
    const int fr = lane & 15, fk = (lane >> 4) * 8;
    f32x4 acc[4][4] = {};
    for (int k0 = 0; k0 < K; k0 += 64) {
        float4 va[4], vb[4];
        #pragma unroll
        for (int j = 0; j < 4; j++) {
            int ci = tid + j * 256; int r = ci >> 3, cc = (ci & 7) * 8;
            va[j] = *(const float4*)(A + (size_t)(m0 + r) * lda + k0 + cc);
            vb[j] = *(const float4*)(B + (size_t)(n0 + r) * ldb + k0 + cc);
        }
        __syncthreads();
        #pragma unroll
        for (int j = 0; j < 4; j++) {
            int ci = tid + j * 256; int r = ci >> 3, cc = (ci & 7) * 8;
            *(float4*)(As + swz(r, cc, 64)) = va[j];
            *(float4*)(Bs + swz(r, cc, 64)) = vb[j];
        }
        __syncthreads();
        #pragma unroll
        for (int ks = 0; ks < 2; ks++) {
            bf16x8 af[4], bfv[4];
            #pragma unroll
            for (int mf = 0; mf < 4; mf++)
                af[mf] = *(bf16x8*)(As + swz(wm + mf * 16 + fr, ks * 32 + fk, 64));
            #pragma unroll
            for (int nf = 0; nf < 4; nf++)
                bfv[nf] = *(bf16x8*)(Bs + swz(wn + nf * 16 + fr, ks * 32 + fk, 64));
            #pragma unroll
            for (int mf = 0; mf < 4; mf++)
                #pragma unroll
                for (int nf = 0; nf < 4; nf++)
                    acc[mf][nf] = MF(af[mf], bfv[nf], acc[mf][nf]);
        }
    }
    #pragma unroll
    for (int mf = 0; mf < 4; mf++) {
        int rb = m0 + wm + mf * 16 + (lane >> 4) * 4;
        #pragma unroll
        for (int nf = 0; nf < 4; nf++) {
            int col = n0 + wn + nf * 16 + fr;
            float bv = HAS_BIAS ? bias[col] : 0.f;
            #pragma unroll
            for (int r = 0; r < 4; r++)
                C[(size_t)(rb + r) * ldc + col] = scale * acc[mf][nf][r] + bv;
        }
    }
}

// ---------- global max over ddk ----------
__global__ __launch_bounds__(256)
void gmax_reduce(const float* __restrict__ dd, u32* __restrict__ out)
{
    const size_t total4 = (size_t)8192 * 2048 / 4;
    size_t stride = (size_t)gridDim.x * 256;
    float lm = -1e30f;
    for (size_t p = (size_t)blockIdx.x * 256 + threadIdx.x; p < total4; p += stride) {
        float4 v = ((const float4*)dd)[p];
        lm = fmaxf(lm, fmaxf(fmaxf(v.x, v.y), fmaxf(v.z, v.w)));
    }
    lm = wave_max(lm);
    if ((threadIdx.x & 63) == 0) {
        u32 u = __float_as_uint(lm);
        u32 key = (u & 0x80000000u) ? ~u : (u | 0x80000000u);
        atomicMax(out, key);
    }
}

// ---------- feature map: phi = 0.0625*(exp(dd - diag - m) + 1e-4), bf16 out ----------
__global__ __launch_bounds__(64)
void feat_fin(const float* __restrict__ dd, const float* __restrict__ lin,
              const u32* __restrict__ gmaxkey, u16* __restrict__ phi, int is_query)
{
    const int blk = blockIdx.x, row = blk >> 3, h = blk & 7, lane = threadIdx.x;
    float q = lin[(size_t)row * 512 + h * 64 + lane];
    float diag = 0.0625f * wave_sum(q * q);
    const float* p = dd + (size_t)row * 2048 + h * 256;
    float4 v = *(const float4*)&p[lane * 4];
    float m;
    if (is_query) m = wave_max(fmaxf(fmaxf(v.x, v.y), fmaxf(v.z, v.w)));
    else {
        u32 key = *gmaxkey;
        u32 ub = (key & 0x80000000u) ? (key & 0x7fffffffu) : ~key;
        m = __uint_as_float(ub);
    }
    float s = diag + m;
    ushort4 o;
    o.x = f2bf(0.0625f * (expf(v.x - s) + 1e-4f));
    o.y = f2bf(0.0625f * (expf(v.y - s) + 1e-4f));
    o.z = f2bf(0.0625f * (expf(v.z - s) + 1e-4f));
    o.w = f2bf(0.0625f * (expf(v.w - s) + 1e-4f));
    *(ushort4*)(phi + (size_t)row * 2048 + h * 256 + lane * 4) = o;
}

// ---------- transpose phiK per chunk -> phiKT[gc][f=256][r=128] ----------
__global__ __launch_bounds__(256)
void transpose_k(const u16* __restrict__ phiK, u16* __restrict__ phiKT)
{
    __shared__ u16 tr[64 * 136];
    const int gc = blockIdx.x, c = gc & 31, bh = gc >> 5, b = bh >> 3, h = bh & 7;
    const int row0 = b * 4096 + c * 128;
    const u16* src = phiK + (size_t)row0 * 2048 + h * 256;
    u16* dst = phiKT + (size_t)gc * 32768;
    const int tid = threadIdx.x;
    for (int f0 = 0; f0 < 256; f0 += 64) {
        #pragma unroll
        for (int j = 0; j < 4; j++) {
            int ci = tid + j * 256; int r = ci >> 3, ff = (ci & 7) * 8;
            bf16x8 w = *(const bf16x8*)(src + (size_t)r * 2048 + f0 + ff);
            #pragma unroll
            for (int q = 0; q < 8; q++) tr[(ff + q) * 136 + r] = (u16)w[q];
        }
        __syncthreads();
        {
            int f = tid >> 2, r0 = (tid & 3) * 32;
            uint4 a0 = *(uint4*)&tr[f * 136 + r0];
            uint4 a1 = *(uint4*)&tr[f * 136 + r0 + 8];
            uint4 a2 = *(uint4*)&tr[f * 136 + r0 + 16];
            uint4 a3 = *(uint4*)&tr[f * 136 + r0 + 24];
            u16* dp = dst + (size_t)(f0 + f) * 128 + r0;
            *(uint4*)dp = a0; *(uint4*)(dp + 8) = a1;
            *(uint4*)(dp + 16) = a2; *(uint4*)(dp + 24) = a3;
        }
        __syncthreads();
    }
}

// ---------- transpose v per chunk -> Vt[gc][plane hi/lo][e=64][r=128] bf16 ----------
__global__ __launch_bounds__(256)
void transpose_v(const float* __restrict__ vlin, u16* __restrict__ Vt)
{
    __shared__ u16 trh[64 * 136];
    __shared__ u16 trl[64 * 136];
    const int gc = blockIdx.x, c = gc & 31, bh = gc >> 5, b = bh >> 3, h = bh & 7;
    const int row0 = b * 4096 + c * 128;
    const float* src = vlin + (size_t)row0 * 512 + h * 64;
    u16* dst = Vt + (size_t)gc * 16384;
    const int tid = threadIdx.x;
    #pragma unroll
    for (int j = 0; j < 8; j++) {
        int ci = tid + j * 256; int r = ci >> 4, e = (ci & 15) * 4;
        float4 v = *(const float4*)(src + (size_t)r * 512 + e);
        float vf[4] = {v.x, v.y, v.z, v.w};
        #pragma unroll
        for (int q = 0; q < 4; q++) {
            u16 hh = f2bf(vf[q]);
            trh[(e + q) * 136 + r] = hh;
            trl[(e + q) * 136 + r] = f2bf(vf[q] - bf2f(hh));
        }
    }
    __syncthreads();
    int e = tid >> 2, r0 = (tid & 3) * 32;
    #pragma unroll
    for (int q = 0; q < 4; q++) {
        uint4 a = *(uint4*)&trh[e * 136 + r0 + q * 8];
        *(uint4*)(dst + (size_t)e * 128 + r0 + q * 8) = a;
    }
    #pragma unroll
    for (int q = 0; q < 4; q++) {
        uint4 a = *(uint4*)&trl[e * 136 + r0 + q * 8];
        *(uint4*)(dst + 8192 + (size_t)e * 128 + r0 + q * 8) = a;
    }
}

// ---------- Pass A: S = K^T (Vhi+Vlo), Z = colsum(K) ----------
__global__ __launch_bounds__(256)
void chunk_sums_mfma(const u16* __restrict__ phiKT, const u16* __restrict__ Vt,
                     float* __restrict__ sbuf, float* __restrict__ zbuf)
{
    __shared__ char smem[49152];
    char* bufA = smem;            // [256 f][64 r] swz
    char* bufBh = smem + 32768;   // [64 e][64 r] swz
    char* bufBl = smem + 40960;
    const int gc = blockIdx.x;
    const u16* Ag = phiKT + (size_t)gc * 32768;
    const u16* Bg = Vt + (size_t)gc * 16384;
    const int tid = threadIdx.x, lane = tid & 63, wave = tid >> 6;
    const int fr = lane & 15, fk = (lane >> 4) * 8;
    {
        float z = 0.f;
        const u16* zp = Ag + (size_t)tid * 128;
        #pragma unroll
        for (int j = 0; j < 16; j++) {
            bf16x8 w = *(const bf16x8*)(zp + j * 8);
            #pragma unroll
            for (int q = 0; q < 8; q++) z += bf2f((u16)w[q]);
        }
        zbuf[(size_t)gc * 256 + tid] = z;
    }
    f32x4 acc[4][4] = {};
    for (int kh = 0; kh < 2; kh++) {
        float4 va[8], vbh[2], vbl[2];
        #pragma unroll
        for (int j = 0; j < 8; j++) {
            int ci = tid + j * 256; int f = ci >> 3, rr = (ci & 7) * 8;
            va[j] = *(const float4*)(Ag + (size_t)f * 128 + kh * 64 + rr);
        }
        #pragma unroll
        for (int j = 0; j < 2; j++) {
            int ci = tid + j * 256; int e = ci >> 3, rr = (ci & 7) * 8;
            vbh[j] = *(const float4*)(Bg + (size_t)e * 128 + kh * 64 + rr);
            vbl[j] = *(const float4*)(Bg + 8192 + (size_t)e * 128 + kh * 64 + rr);
        }
        __syncthreads();
        #pragma unroll
        for (int j = 0; j < 8; j++) {
            int ci = tid + j * 256; int f = ci >> 3, rr = (ci & 7) * 8;
            *(float4*)(bufA + swz(f, rr, 64)) = va[j];
        }
        #pragma unroll
        for (int j = 0; j < 2; j++) {
            int ci = tid + j * 256; int e = ci >> 3, rr = (ci & 7) * 8;
            *(float4*)(bufBh + swz(e, rr, 64)) = vbh[j];
            *(float4*)(bufBl + swz(e, rr, 64)) = vbl[j];
        }
        __syncthreads();
        #pragma unroll
        for (int ks = 0; ks < 2; ks++) {
            bf16x8 af[4], bh4[4], bl4[4];
            #pragma unroll
            for (int mf = 0; mf < 4; mf++)
                af[mf] = *(bf16x8*)(bufA + swz(wave * 64 + mf * 16 + fr, ks * 32 + fk, 64));
            #pragma unroll
            for (int nf = 0; nf < 4; nf++) {
                bh4[nf] = *(bf16x8*)(bufBh + swz(nf * 16 + fr, ks * 32 + fk, 64));
                bl4[nf] = *(bf16x8*)(bufBl + swz(nf * 16 + fr, ks * 32 + fk, 64));
            }
            #pragma unroll
            for (int mf = 0; mf < 4; mf++)
                #pragma unroll
                for (int nf = 0; nf < 4; nf++) {
                    acc[mf][nf] = MF(af[mf], bh4[nf], acc[mf][nf]);
                    acc[mf][nf] = MF(af[mf], bl4[nf], acc[mf][nf]);
                }
        }
        __syncthreads();
    }
    #pragma unroll
    for (int mf = 0; mf < 4; mf++) {
        int fb = wave * 64 + mf * 16 + (lane >> 4) * 4;
        #pragma unroll
        for (int nf = 0; nf < 4; nf++) {
            int e = nf * 16 + fr;
            #pragma unroll
            for (int r = 0; r < 4; r++)
                sbuf[(size_t)gc * 16384 + (size_t)(fb + r) * 64 + e] = acc[mf][nf][r];
        }
    }
}

// ---------- Pass B: exclusive prefix; SpT hi/lo bf16 [gc][pl][e][f], Zp f32 ----------
__global__ __launch_bounds__(256)
void prefix_scan(float* __restrict__ sbuf, const float* __restrict__ zbuf,
                 u16* __restrict__ SpT, float* __restrict__ Zp,
                 float* __restrict__ outZ, float* __restrict__ outS)
{
    __shared__ float trans[64 * 68];
    const int bh = blockIdx.x >> 2, f0 = (blockIdx.x & 3) * 64;
    const int tid = threadIdx.x;
    float run[16];
    #pragma unroll
    for (int i = 0; i < 16; i++) run[i] = 0.f;
    float zrun = 0.f;
    for (int c = 0; c < 32; c++) {
        const int gc = bh * 32 + c;
        const float* base = sbuf + (size_t)gc * 16384 + f0 * 64;
        float v[16];
        #pragma unroll
        for (int i = 0; i < 16; i++) v[i] = base[tid + i * 256];
        #pragma unroll
        for (int i = 0; i < 16; i++) {
            int idx = tid + i * 256;
            trans[(idx & 63) * 68 + (idx >> 6)] = run[i];
        }
        float zv = 0.f;
        if (tid < 64) zv = zbuf[(size_t)gc * 256 + f0 + tid];
        __syncthreads();
        {
            int e = tid >> 2, fl = (tid & 3) * 16;
            float* tp = &trans[e * 68 + fl];
            alignas(16) u16 hbuf[16], lbuf[16];
            #pragma unroll
            for (int q = 0; q < 16; q++) {
                float vv = tp[q];
                u16 hh = f2bf(vv);
                hbuf[q] = hh;
                lbuf[q] = f2bf(vv - bf2f(hh));
            }
            u16* dh = SpT + (size_t)gc * 32768 + e * 256 + f0 + fl;
            *(uint4*)dh = *(uint4*)&hbuf[0];
            *(uint4*)(dh + 8) = *(uint4*)&hbuf[8];
            u16* dl = dh + 16384;
            *(uint4*)dl = *(uint4*)&lbuf[0];
            *(uint4*)(dl + 8) = *(uint4*)&lbuf[8];
        }
        if (tid < 64) { Zp[(size_t)gc * 256 + f0 + tid] = zrun; zrun += zv; }
        #pragma unroll
        for (int i = 0; i < 16; i++) run[i] += v[i];
        __syncthreads();
    }
    #pragma unroll
    for (int i = 0; i < 16; i++)
        outS[(size_t)bh * 16384 + f0 * 64 + tid + i * 256] = run[i];
    if (tid < 64) outZ[bh * 256 + f0 + tid] = zrun;
}

// ---------- Pass C: aout = Dinv*(Q@Sprev + tril(QK^T)@V), all MFMA ----------
__global__ __launch_bounds__(256)
void chunk_out_mfma(const u16* __restrict__ phiQ, const u16* __restrict__ phiK,
                    const u16* __restrict__ Vt, const u16* __restrict__ SpT,
                    const float* __restrict__ Zp, float* __restrict__ aout)
{
    extern __shared__ char sm[];
    char* bufQ = sm;             // [128][64] swz Q-slab ; later V_lo [64][128] swz
    char* bufK = sm + 16384;     // [128][64] swz K-slab ; later V_hi [64][128] swz
    char* bufA = sm + 32768;     // during f0 loop: Sp_hi [64][64] @+0, Sp_lo @+8192 ; after: A [128][128] swz
    float* Dl = (float*)(sm + 65536);    // [128]
    float* Zl = (float*)(sm + 66048);    // [64]
    const int gc = blockIdx.x, c = gc & 31, bh = gc >> 5, b = bh >> 3, h = bh & 7;
    const int row0 = b * 4096 + c * 128;
    const u16* Qg = phiQ + (size_t)row0 * 2048 + h * 256;
    const u16* Kg = phiK + (size_t)row0 * 2048 + h * 256;
    const u16* Vg = Vt + (size_t)gc * 16384;
    const u16* Sg = SpT + (size_t)gc * 32768;
    const float* Zg = Zp + (size_t)gc * 256;
    const int tid = threadIdx.x, lane = tid & 63, wave = tid >> 6;
    const int fr = lane & 15, fk = (lane >> 4) * 8;
    const int dr = tid >> 1, dc = (tid & 1) * 32;

    f32x4 acc2[2][8] = {};   // QK^T: rows wave*32.., 128 cols
    f32x4 acc1[2][4] = {};   // out:  rows wave*32.., 64 e
    float dotZ = 0.f, sumQ = 0.f;

    for (int f0 = 0; f0 < 256; f0 += 64) {
        float4 vq[4], vk[4], vsh[2], vsl[2];
        #pragma unroll
        for (int j = 0; j < 4; j++) {
            int ci = tid + j * 256; int r = ci >> 3, cc = (ci & 7) * 8;
            vq[j] = *(const float4*)(Qg + (size_t)r * 2048 + f0 + cc);
            vk[j] = *(const float4*)(Kg + (size_t)r * 2048 + f0 + cc);
        }
        #pragma unroll
        for (int j = 0; j < 2; j++) {
            int ci = tid + j * 256; int e = ci >> 3, cc = (ci & 7) * 8;
            vsh[j] = *(const float4*)(Sg + (size_t)e * 256 + f0 + cc);
            vsl[j] = *(const float4*)(Sg + 16384 + (size_t)e * 256 + f0 + cc);
        }
        __syncthreads();
        #pragma unroll
        for (int j = 0; j < 4; j++) {
            int ci = tid + j * 256; int r = ci >> 3, cc = (ci & 7) * 8;
            *(float4*)(bufQ + swz(r, cc, 64)) = vq[j];
            *(float4*)(bufK + swz(r, cc, 64)) = vk[j];
        }
        #pragma unroll
        for (int j = 0; j < 2; j++) {
            int ci = tid + j * 256; int e = ci >> 3, cc = (ci & 7) * 8;
            *(float4*)(bufA + swz(e, cc, 64)) = vsh[j];
            *(float4*)(bufA + 8192 + swz(e, cc, 64)) = vsl[j];
        }
        if (tid < 64) Zl[tid] = Zg[f0 + tid];
        __syncthreads();
        #pragma unroll
        for (int ks = 0; ks < 2; ks++) {
            bf16x8 af[2];
            af[0] = *(bf16x8*)(bufQ + swz(wave * 32 + fr, ks * 32 + fk, 64));
            af[1] = *(bf16x8*)(bufQ + swz(wave * 32 + 16 + fr, ks * 32 + fk, 64));
            #pragma unroll
            for (int nf = 0; nf < 8; nf++) {
                bf16x8 bv = *(bf16x8*)(bufK + swz(nf * 16 + fr, ks * 32 + fk, 64));
                acc2[0][nf] = MF(af[0], bv, acc2[0][nf]);
                acc2[1][nf] = MF(af[1], bv, acc2[1][nf]);
            }
            #pragma unroll
            for (int nf = 0; nf < 4; nf++) {
                bf16x8 bvh = *(bf16x8*)(bufA + swz(nf * 16 + fr, ks * 32 + fk, 64));
                bf16x8 bvl = *(bf16x8*)(bufA + 8192 + swz(nf * 16 + fr, ks * 32 + fk, 64));
                acc1[0][nf] = MF(af[0], bvh, acc1[0][nf]);
                acc1[1][nf] = MF(af[1], bvh, acc1[1][nf]);
                acc1[0][nf] = MF(af[0], bvl, acc1[0][nf]);
                acc1[1][nf] = MF(af[1], bvl, acc1[1][nf]);
            }
        }
        // D partials: row dr, cols dc..dc+31 of this 64-wide f-slab
        #pragma unroll
        for (int jj = 0; jj < 4; jj++) {
            bf16x8 qv = *(bf16x8*)(bufQ + swz(dr, dc + jj * 8, 64));
            f32x4 z0 = *(f32x4*)(Zl + dc + jj * 8);
            f32x4 z1 = *(f32x4*)(Zl + dc + jj * 8 + 4);
            #pragma unroll
            for (int q = 0; q < 8; q++) {
                float qf = bf2f((u16)qv[q]);
                sumQ += qf;
                dotZ += qf * (q < 4 ? z0[q] : z1[q - 4]);
            }
        }
    }
    __syncthreads();
    // stage V hi/lo (regs) + write tril(A) bf16 into bufA
    float4 vvh[4], vvl[4];
    #pragma unroll
    for (int j = 0; j < 4; j++) {
        int ci = tid + j * 256; int e = ci >> 4, cc = (ci & 15) * 8;
        vvh[j] = *(const float4*)(Vg + (size_t)e * 128 + cc);
        vvl[j] = *(const float4*)(Vg + 8192 + (size_t)e * 128 + cc);
    }
    #pragma unroll
    for (int mf = 0; mf < 2; mf++) {
        int rb = wave * 32 + mf * 16 + (lane >> 4) * 4;
        #pragma unroll
        for (int nf = 0; nf < 8; nf++) {
            int col = nf * 16 + fr;
            #pragma unroll
            for (int r = 0; r < 4; r++) {
                float v = (col <= rb + r) ? acc2[mf][nf][r] : 0.f;
                *(u16*)(bufA + swz(rb + r, col, 128)) = f2bf(v);
            }
        }
    }
    #pragma unroll
    for (int j = 0; j < 4; j++) {
        int ci = tid + j * 256; int e = ci >> 4, cc = (ci & 15) * 8;
        *(float4*)(bufK + swz(e, cc, 128)) = vvh[j];
        *(float4*)(bufQ + swz(e, cc, 128)) = vvl[j];
    }
    __syncthreads();
    // D row totals: FULL 128-col rowsum of bf16 A (2 threads/row, 64 cols each)
    {
        const int dcA = (tid & 1) * 64;
        float rs = 0.f;
        #pragma unroll
        for (int jj = 0; jj < 8; jj++) {
            bf16x8 av = *(bf16x8*)(bufA + swz(dr, dcA + jj * 8, 128));
            #pragma unroll
            for (int q = 0; q < 8; q++) rs += bf2f((u16)av[q]);
        }
        float tot = rs + dotZ + 1e-6f * sumQ;
        tot += __shfl_xor(tot, 1);
        if ((tid & 1) == 0) Dl[dr] = tot;
    }
    // phase 3: out += tril(A) @ (Vhi + Vlo)
    #pragma unroll
    for (int ks = 0; ks < 4; ks++) {
        bf16x8 af[2];
        af[0] = *(bf16x8*)(bufA + swz(wave * 32 + fr, ks * 32 + fk, 128));
        af[1] = *(bf16x8*)(bufA + swz(wave * 32 + 16 + fr, ks * 32 + fk, 128));
        #pragma unroll
        for (int nf = 0; nf < 4; nf++) {
            bf16x8 bvh = *(bf16x8*)(bufK + swz(nf * 16 + fr, ks * 32 + fk, 128));
            bf16x8 bvl = *(bf16x8*)(bufQ + swz(nf * 16 + fr, ks * 32 + fk, 128));
            acc1[0][nf] = MF(af[0], bvh, acc1[0][nf]);
            acc1[1][nf] = MF(af[1], bvh, acc1[1][nf]);
            acc1[0][nf] = MF(af[0], bvl, acc1[0][nf]);
            acc1[1][nf] = MF(af[1], bvl, acc1[1][nf]);
        }
    }
    __syncthreads();
    #pragma unroll
    for (int mf = 0; mf < 2; mf++) {
        int rb = wave * 32 + mf * 16 + (lane >> 4) * 4;
        #pragma unroll
        for (int r = 0; r < 4; r++) {
            float dinv = 1.f / Dl[rb + r];
            #pragma unroll
            for (int nf = 0; nf < 4; nf++)
                aout[(size_t)(row0 + rb + r) * 512 + h * 64 + nf * 16 + fr]
                    = acc1[mf][nf][r] * dinv;
        }
    }
}

extern "C" void kernel_launch(void* const* d_in, const int* in_sizes, int n_in,
                              void* d_out, int out_size, void* d_ws, size_t ws_size,
                              hipStream_t stream)
{
    const float* x    = (const float*)d_in[0];
    const float* Wq   = (const float*)d_in[1];
    const float* Wk   = (const float*)d_in[2];
    const float* Wv   = (const float*)d_in[3];
    const float* Wo   = (const float*)d_in[4];
    const float* bo   = (const float*)d_in[5];
    const float* proj = (const float*)d_in[6];
    float* out = (float*)d_out;
    float* ws = (float*)d_ws;

    float* qlin = ws;                           // 4M f32
    float* klin = ws + 4194304;                 // 4M
    float* vlin = ws + 8388608;                 // 4M (reused as f32 aout)
    float* ddq  = ws + 12582912;                // 16M f32
    u16*   phiKT = (u16*)ddq;                   //   overlays ddq after feat (8.4M f)
    u16*   Vtb   = (u16*)(ws + 20971520);       //   [512][2][64][128] (4.2M f)
    float* ddk  = ws + 29360128;                // 16M f32
    float* sbuf = ws + 29360128;                //   overlays ddk (8M f)
    u16*   SpT  = (u16*)(ws + 37748736);        //   [512][2][64][256] (8.4M f)
    float* zbuf = ws + 46137344;                // 128K
    float* Zp   = ws + 46268416;                // 128K
    u32*   gmax = (u32*)(ws + 46399488);
    u16* xs  = (u16*)(ws + 46399552);           // [8192][1536]
    u16* qs  = (u16*)(ws + 52691008);           // [65536][192]
    u16* ks  = (u16*)(ws + 58982464);           // [65536][192]
    u16* phiQ = (u16*)(ws + 46399552);          // overlays xs/qs (dead)
    u16* phiK = (u16*)(ws + 54788160);          // overlays qs/ks (dead)
    u16* aouts = (u16*)(ws + 46399552);         // overlays phiQ (dead)
    float* WR = ws + 65273920;
    u16* Wqs = (u16*)WR;
    u16* Wks = (u16*)(WR + 393216);
    u16* Wvs = (u16*)(WR + 786432);
    u16* Wos = (u16*)(WR + 1179648);
    u16* projs = (u16*)(WR + 1572864);

    float* outO = out;                 // [2,4096,512]
    float* outZ = out + 4194304;       // [2,8,256]
    float* outS = out + 4198400;       // [2,8,256,64]

    const float dn = 0.35355339059327373f;  // 64^-0.25
    dim3 blk(256);

    conv_split<false><<<2048, blk, 0, stream>>>(x, xs, 512, 1048576L, 1.f);
    conv_split<true ><<<256, blk, 0, stream>>>(Wq, Wqs, 512, 65536L, 1.f);
    conv_split<true ><<<256, blk, 0, stream>>>(Wk, Wks, 512, 65536L, 1.f);
    conv_split<true ><<<256, blk, 0, stream>>>(Wv, Wvs, 512, 65536L, 1.f);
    conv_split<true ><<<256, blk, 0, stream>>>(Wo, Wos, 512, 65536L, 1.f);
    conv_split<true ><<<16, blk, 0, stream>>>(proj, projs, 64, 4096L, 1.f);
    gemm_mfma<false><<<dim3(64, 4, 1), blk, 0, stream>>>(xs, 1536, 0, Wqs, 1536, 0, qlin, 512, 0, nullptr, 1536, 1.f);
    gemm_mfma<false><<<dim3(64, 4, 1), blk, 0, stream>>>(xs, 1536, 0, Wks, 1536, 0, klin, 512, 0, nullptr, 1536, 1.f);
    gemm_mfma<false><<<dim3(64, 4, 1), blk, 0, stream>>>(xs, 1536, 0, Wvs, 1536, 0, vlin, 512, 0, nullptr, 1536, 1.f);
    conv_split<false><<<2048, blk, 0, stream>>>(qlin, qs, 64, 1048576L, dn);
    conv_split<false><<<2048, blk, 0, stream>>>(klin, ks, 64, 1048576L, dn);
    gemm_mfma<false><<<dim3(64, 2, 8), blk, 0, stream>>>(qs, 1536, 192, projs, 192, 0, ddq, 2048, 256, nullptr, 192, 1.f);
    gemm_mfma<false><<<dim3(64, 2, 8), blk, 0, stream>>>(ks, 1536, 192, projs, 192, 0, ddk, 2048, 256, nullptr, 192, 1.f);
    hipMemsetAsync(gmax, 0, 4, stream);
    gmax_reduce<<<2048, blk, 0, stream>>>(ddk, gmax);
    feat_fin<<<65536, 64, 0, stream>>>(ddq, qlin, nullptr, phiQ, 1);
    feat_fin<<<65536, 64, 0, stream>>>(ddk, klin, gmax, phiK, 0);
    transpose_k<<<512, blk, 0, stream>>>(phiK, phiKT);
    transpose_v<<<512, blk, 0, stream>>>(vlin, Vtb);
    chunk_sums_mfma<<<512, blk, 0, stream>>>(phiKT, Vtb, sbuf, zbuf);
    prefix_scan<<<64, blk, 0, stream>>>(sbuf, zbuf, SpT, Zp, outZ, outS);
    hipFuncSetAttribute((const void*)chunk_out_mfma,
                        hipFuncAttributeMaxDynamicSharedMemorySize, 66304);
    chunk_out_mfma<<<512, blk, 66304, stream>>>(phiQ, phiK, Vtb, SpT, Zp, vlin);
    conv_split<false><<<2048, blk, 0, stream>>>(vlin, aouts, 512, 1048576L, 1.f);
    gemm_mfma<true><<<dim3(64, 4, 1), blk, 0, stream>>>(aouts, 1536, 0, Wos, 1536, 0, outO, 512, 0, bo, 1536, 1.f);
}

// Round 4
// 563.039 us; speedup vs baseline: 2.0355x; 1.2665x over previous
//
#include <hip/hip_runtime.h>

#define NH 8
#define DH 64
#define FF 256
#define CH 128

typedef unsigned short u16;
typedef unsigned int u32;
typedef __attribute__((ext_vector_type(8))) short bf16x8;
typedef __attribute__((ext_vector_type(4))) float f32x4;

__device__ __forceinline__ u16 f2bf(float f) {
    u32 u = __float_as_uint(f);
    return (u16)((u + 0x7fffu + ((u >> 16) & 1u)) >> 16);
}
__device__ __forceinline__ float bf2f(u16 h) { return __uint_as_float(((u32)h) << 16); }
__device__ __forceinline__ u32 pk(u16 a, u16 b) { return (u32)a | ((u32)b << 16); }
// XOR-swizzled byte offset for bf16 LDS tiles (ld = row elems, mult of 64)
__device__ __forceinline__ int swz(int row, int col, int ld) {
    return ((row * ld + col) * 2) ^ ((row & 7) << 4);
}
__device__ __forceinline__ f32x4 MF(bf16x8 a, bf16x8 b, f32x4 c) {
    return __builtin_amdgcn_mfma_f32_16x16x32_bf16(a, b, c, 0, 0, 0);
}
__device__ __forceinline__ float wave_max(float v) {
    #pragma unroll
    for (int o = 32; o; o >>= 1) v = fmaxf(v, __shfl_xor(v, o));
    return v;
}
__device__ __forceinline__ float wave_sum(float v) {
    #pragma unroll
    for (int o = 32; o; o >>= 1) v += __shfl_xor(v, o);
    return v;
}

// ---------- split-bf16 convert: A:[hi|hi|lo]  B:[hi|lo|hi] ----------
template<bool ISB>
__global__ __launch_bounds__(256)
void conv_split(const float* __restrict__ src, u16* __restrict__ dst,
                int K, long total4, float scale)
{
    const int K4 = K >> 2;
    for (long i = (long)blockIdx.x * 256 + threadIdx.x; i < total4;
         i += (long)gridDim.x * 256) {
        long row = i / K4;
        int c = (int)(i - row * K4) * 4;
        float4 v = ((const float4*)src)[i];
        float a0 = v.x * scale, a1 = v.y * scale, a2 = v.z * scale, a3 = v.w * scale;
        u16 h0 = f2bf(a0), h1 = f2bf(a1), h2 = f2bf(a2), h3 = f2bf(a3);
        u16 l0 = f2bf(a0 - bf2f(h0)), l1 = f2bf(a1 - bf2f(h1));
        u16 l2 = f2bf(a2 - bf2f(h2)), l3 = f2bf(a3 - bf2f(h3));
        uint2 hh; hh.x = pk(h0, h1); hh.y = pk(h2, h3);
        uint2 ll; ll.x = pk(l0, l1); ll.y = pk(l2, l3);
        u16* d = dst + row * (3L * K) + c;
        *(uint2*)d = hh;
        *(uint2*)(d + (ISB ? 2 * K : K)) = hh;
        *(uint2*)(d + (ISB ? K : 2 * K)) = ll;
    }
}

// ---------- split convert of q,k head slices from qkv[8192][1536] -> qs/ks [row][h][192] ----------
__global__ __launch_bounds__(256)
void conv_qk(const float* __restrict__ qkv, u16* __restrict__ qs)
{
    const float dn = 0.35355339059327373f; // 64^-0.25
    for (long i = (long)blockIdx.x * 256 + threadIdx.x; i < 2097152L;
         i += (long)gridDim.x * 256) {
        int which = i >= 1048576L;               // 0=q, 1=k
        long t = i - (long)which * 1048576L;     // r*128 + h*16 + jq
        int r = (int)(t >> 7);
        int h = ((int)t >> 4) & 7;
        int jq = ((int)t & 15) * 4;
        const float* s = qkv + (size_t)r * 1536 + which * 512 + h * 64 + jq;
        float4 v = *(const float4*)s;
        float a0 = v.x * dn, a1 = v.y * dn, a2 = v.z * dn, a3 = v.w * dn;
        u16 h0 = f2bf(a0), h1 = f2bf(a1), h2 = f2bf(a2), h3 = f2bf(a3);
        u16 l0 = f2bf(a0 - bf2f(h0)), l1 = f2bf(a1 - bf2f(h1));
        u16 l2 = f2bf(a2 - bf2f(h2)), l3 = f2bf(a3 - bf2f(h3));
        uint2 hh; hh.x = pk(h0, h1); hh.y = pk(h2, h3);
        uint2 ll; ll.x = pk(l0, l1); ll.y = pk(l2, l3);
        u16* d = qs + (size_t)which * 12582912 + (size_t)r * 1536 + h * 192 + jq;
        *(uint2*)d = hh;
        *(uint2*)(d + 64) = hh;
        *(uint2*)(d + 128) = ll;
    }
}

// ---------- bf16 MFMA NT GEMM: C = scale * A @ B^T (+bias). 128x128 tile, BK=64 ----------
// optional fused max: blocks with blockIdx.x >= umaxMinBX atomicMax ordered-key of tile max
template<bool HAS_BIAS>
__global__ __launch_bounds__(256, 2)
void gemm_mfma(const u16* __restrict__ A, int lda, int zA,
               const u16* __restrict__ B, int ldb, int zB,
               float* __restrict__ C, int ldc, int zC,
               const float* __restrict__ bias, int K, float scale,
               u32* umax, int umaxMinBX)
{
    __shared__ char smem[32768];
    __shared__ float redbuf[4];
    char* As = smem; char* Bs = smem + 16384;
    A += (size_t)blockIdx.z * zA; B += (size_t)blockIdx.z * zB; C += (size_t)blockIdx.z * zC;
    const int m0 = blockIdx.x * 128, n0 = blockIdx.y * 128;
    const int tid = threadIdx.x, lane = tid & 63, wave = tid >> 6;
    const int wm = (wave >> 1) * 64, wn = (wave & 1) * 64;
    const int fr = lane & 15, fk = (lane >> 4) * 8;
    f32x4 acc[4][4] = {};
    for (int k0 = 0; k0 < K; k0 += 64) {
        float4 va[4], vb[4];
        #pragma unroll
        for (int j = 0; j < 4; j++) {
            int ci = tid + j * 256; int r = ci >> 3, cc = (ci & 7) * 8;
            va[j] = *(const float4*)(A + (size_t)(m0 + r) * lda + k0 + cc);
            vb[j] = *(const float4*)(B + (size_t)(n0 + r) * ldb + k0 + cc);
        }
        __syncthreads();
        #pragma unroll
        for (int j = 0; j < 4; j++) {
            int ci = tid + j * 256; int r = ci >> 3, cc = (ci & 7) * 8;
            *(float4*)(As + swz(r, cc, 64)) = va[j];
            *(float4*)(Bs + swz(r, cc, 64)) = vb[j];
        }
        __syncthreads();
        #pragma unroll
        for (int ks = 0; ks < 2; ks++) {
            bf16x8 af[4], bfv[4];
            #pragma unroll
            for (int mf = 0; mf < 4; mf++)
                af[mf] = *(bf16x8*)(As + swz(wm + mf * 16 + fr, ks * 32 + fk, 64));
            #pragma unroll
            for (int nf = 0; nf < 4; nf++)
                bfv[nf] = *(bf16x8*)(Bs + swz(wn + nf * 16 + fr, ks * 32 + fk, 64));
            #pragma unroll
            for (int mf = 0; mf < 4; mf++)
                #pragma unroll
                for (int nf = 0; nf < 4; nf++)
                    acc[mf][nf] = MF(af[mf], bfv[nf], acc[mf][nf]);
        }
    }
    float mx = -1e30f;
    #pragma unroll
    for (int mf = 0; mf < 4; mf++) {
        int rb = m0 + wm + mf * 16 + (lane >> 4) * 4;
        #pragma unroll
        for (int nf = 0; nf < 4; nf++) {
            int col = n0 + wn + nf * 16 + fr;
            float bv = HAS_BIAS ? bias[col] : 0.f;
            #pragma unroll
            for (int r = 0; r < 4; r++) {
                float v = scale * acc[mf][nf][r] + bv;
                C[(size_t)(rb + r) * ldc + col] = v;
                mx = fmaxf(mx, v);
            }
        }
    }
    if (umax && (int)blockIdx.x >= umaxMinBX) {
        mx = wave_max(mx);
        if (lane == 0) redbuf[wave] = mx;
        __syncthreads();
        if (tid == 0) {
            float m4 = fmaxf(fmaxf(redbuf[0], redbuf[1]), fmaxf(redbuf[2], redbuf[3]));
            u32 u = __float_as_uint(m4);
            u32 key = (u & 0x80000000u) ? ~u : (u | 0x80000000u);
            atomicMax(umax, key);
        }
    }
}

// ---------- feature map (q+k fused): phi = 0.0625*(exp(dd - diag - m) + 1e-4), bf16 out ----------
// dd [16384][2048]: rows <8192 = q (per-row-head max), rows >=8192 = k (global max)
__global__ __launch_bounds__(256)
void feat_fin(const float* __restrict__ dd, const float* __restrict__ qkv,
              const u32* __restrict__ gmaxkey, u16* __restrict__ phi)
{
    const int u = blockIdx.x * 4 + (threadIdx.x >> 6);
    const int lane = threadIdx.x & 63;
    const int row = u >> 3, h = u & 7;
    const int isq = row < 8192;
    float q = isq ? qkv[(size_t)row * 1536 + h * 64 + lane]
                  : qkv[(size_t)(row - 8192) * 1536 + 512 + h * 64 + lane];
    float diag = 0.0625f * wave_sum(q * q);
    const float* p = dd + (size_t)row * 2048 + h * 256;
    float4 v = *(const float4*)&p[lane * 4];
    float m;
    if (isq) {
        m = wave_max(fmaxf(fmaxf(v.x, v.y), fmaxf(v.z, v.w)));
    } else {
        u32 key = *gmaxkey;
        u32 ub = (key & 0x80000000u) ? (key & 0x7fffffffu) : ~key;
        m = __uint_as_float(ub);
    }
    float s = diag + m;
    ushort4 o;
    o.x = f2bf(0.0625f * (expf(v.x - s) + 1e-4f));
    o.y = f2bf(0.0625f * (expf(v.y - s) + 1e-4f));
    o.z = f2bf(0.0625f * (expf(v.z - s) + 1e-4f));
    o.w = f2bf(0.0625f * (expf(v.w - s) + 1e-4f));
    *(ushort4*)(phi + (size_t)row * 2048 + h * 256 + lane * 4) = o;
}

// ---------- transpose phiK per chunk -> phiKT[gc][f=256][r=128] ----------
__global__ __launch_bounds__(256)
void transpose_k(const u16* __restrict__ phiK, u16* __restrict__ phiKT)
{
    __shared__ u16 tr[64 * 136];
    const int gc = blockIdx.x, c = gc & 31, bh = gc >> 5, b = bh >> 3, h = bh & 7;
    const int row0 = b * 4096 + c * 128;
    const u16* src = phiK + (size_t)row0 * 2048 + h * 256;
    u16* dst = phiKT + (size_t)gc * 32768;
    const int tid = threadIdx.x;
    for (int f0 = 0; f0 < 256; f0 += 64) {
        #pragma unroll
        for (int j = 0; j < 4; j++) {
            int ci = tid + j * 256; int r = ci >> 3, ff = (ci & 7) * 8;
            bf16x8 w = *(const bf16x8*)(src + (size_t)r * 2048 + f0 + ff);
            #pragma unroll
            for (int q = 0; q < 8; q++) tr[(ff + q) * 136 + r] = (u16)w[q];
        }
        __syncthreads();
        {
            int f = tid >> 2, r0 = (tid & 3) * 32;
            uint4 a0 = *(uint4*)&tr[f * 136 + r0];
            uint4 a1 = *(uint4*)&tr[f * 136 + r0 + 8];
            uint4 a2 = *(uint4*)&tr[f * 136 + r0 + 16];
            uint4 a3 = *(uint4*)&tr[f * 136 + r0 + 24];
            u16* dp = dst + (size_t)(f0 + f) * 128 + r0;
            *(uint4*)dp = a0; *(uint4*)(dp + 8) = a1;
            *(uint4*)(dp + 16) = a2; *(uint4*)(dp + 24) = a3;
        }
        __syncthreads();
    }
}

// ---------- transpose v per chunk -> Vt[gc][plane hi/lo][e=64][r=128] bf16 ----------
__global__ __launch_bounds__(256)
void transpose_v(const float* __restrict__ vsrc, u16* __restrict__ Vt, int srcLd)
{
    __shared__ u16 trh[64 * 136];
    __shared__ u16 trl[64 * 136];
    const int gc = blockIdx.x, c = gc & 31, bh = gc >> 5, b = bh >> 3, h = bh & 7;
    const int row0 = b * 4096 + c * 128;
    const float* src = vsrc + (size_t)row0 * srcLd + h * 64;
    u16* dst = Vt + (size_t)gc * 16384;
    const int tid = threadIdx.x;
    #pragma unroll
    for (int j = 0; j < 8; j++) {
        int ci = tid + j * 256; int r = ci >> 4, e = (ci & 15) * 4;
        float4 v = *(const float4*)(src + (size_t)r * srcLd + e);
        float vf[4] = {v.x, v.y, v.z, v.w};
        #pragma unroll
        for (int q = 0; q < 4; q++) {
            u16 hh = f2bf(vf[q]);
            trh[(e + q) * 136 + r] = hh;
            trl[(e + q) * 136 + r] = f2bf(vf[q] - bf2f(hh));
        }
    }
    __syncthreads();
    int e = tid >> 2, r0 = (tid & 3) * 32;
    #pragma unroll
    for (int q = 0; q < 4; q++) {
        uint4 a = *(uint4*)&trh[e * 136 + r0 + q * 8];
        *(uint4*)(dst + (size_t)e * 128 + r0 + q * 8) = a;
    }
    #pragma unroll
    for (int q = 0; q < 4; q++) {
        uint4 a = *(uint4*)&trl[e * 136 + r0 + q * 8];
        *(uint4*)(dst + 8192 + (size_t)e * 128 + r0 + q * 8) = a;
    }
}

// ---------- Pass A: S = K^T (Vhi+Vlo), Z = colsum(K) ----------
__global__ __launch_bounds__(256)
void chunk_sums_mfma(const u16* __restrict__ phiKT, const u16* __restrict__ Vt,
                     float* __restrict__ sbuf, float* __restrict__ zbuf)
{
    __shared__ char smem[49152];
    char* bufA = smem;            // [256 f][64 r] swz
    char* bufBh = smem + 32768;   // [64 e][64 r] swz
    char* bufBl = smem + 40960;
    const int gc = blockIdx.x;
    const u16* Ag = phiKT + (size_t)gc * 32768;
    const u16* Bg = Vt + (size_t)gc * 16384;
    const int tid = threadIdx.x, lane = tid & 63, wave = tid >> 6;
    const int fr = lane & 15, fk = (lane >> 4) * 8;
    {
        float z = 0.f;
        const u16* zp = Ag + (size_t)tid * 128;
        #pragma unroll
        for (int j = 0; j < 16; j++) {
            bf16x8 w = *(const bf16x8*)(zp + j * 8);
            #pragma unroll
            for (int q = 0; q < 8; q++) z += bf2f((u16)w[q]);
        }
        zbuf[(size_t)gc * 256 + tid] = z;
    }
    f32x4 acc[4][4] = {};
    for (int kh = 0; kh < 2; kh++) {
        float4 va[8], vbh[2], vbl[2];
        #pragma unroll
        for (int j = 0; j < 8; j++) {
            int ci = tid + j * 256; int f = ci >> 3, rr = (ci & 7) * 8;
            va[j] = *(const float4*)(Ag + (size_t)f * 128 + kh * 64 + rr);
        }
        #pragma unroll
        for (int j = 0; j < 2; j++) {
            int ci = tid + j * 256; int e = ci >> 3, rr = (ci & 7) * 8;
            vbh[j] = *(const float4*)(Bg + (size_t)e * 128 + kh * 64 + rr);
            vbl[j] = *(const float4*)(Bg + 8192 + (size_t)e * 128 + kh * 64 + rr);
        }
        __syncthreads();
        #pragma unroll
        for (int j = 0; j < 8; j++) {
            int ci = tid + j * 256; int f = ci >> 3, rr = (ci & 7) * 8;
            *(float4*)(bufA + swz(f, rr, 64)) = va[j];
        }
        #pragma unroll
        for (int j = 0; j < 2; j++) {
            int ci = tid + j * 256; int e = ci >> 3, rr = (ci & 7) * 8;
            *(float4*)(bufBh + swz(e, rr, 64)) = vbh[j];
            *(float4*)(bufBl + swz(e, rr, 64)) = vbl[j];
        }
        __syncthreads();
        #pragma unroll
        for (int ks = 0; ks < 2; ks++) {
            bf16x8 af[4], bh4[4], bl4[4];
            #pragma unroll
            for (int mf = 0; mf < 4; mf++)
                af[mf] = *(bf16x8*)(bufA + swz(wave * 64 + mf * 16 + fr, ks * 32 + fk, 64));
            #pragma unroll
            for (int nf = 0; nf < 4; nf++) {
                bh4[nf] = *(bf16x8*)(bufBh + swz(nf * 16 + fr, ks * 32 + fk, 64));
                bl4[nf] = *(bf16x8*)(bufBl + swz(nf * 16 + fr, ks * 32 + fk, 64));
            }
            #pragma unroll
            for (int mf = 0; mf < 4; mf++)
                #pragma unroll
                for (int nf = 0; nf < 4; nf++) {
                    acc[mf][nf] = MF(af[mf], bh4[nf], acc[mf][nf]);
                    acc[mf][nf] = MF(af[mf], bl4[nf], acc[mf][nf]);
                }
        }
        __syncthreads();
    }
    #pragma unroll
    for (int mf = 0; mf < 4; mf++) {
        int fb = wave * 64 + mf * 16 + (lane >> 4) * 4;
        #pragma unroll
        for (int nf = 0; nf < 4; nf++) {
            int e = nf * 16 + fr;
            #pragma unroll
            for (int r = 0; r < 4; r++)
                sbuf[(size_t)gc * 16384 + (size_t)(fb + r) * 64 + e] = acc[mf][nf][r];
        }
    }
}

// ---------- Pass B: exclusive prefix; SpT hi/lo bf16 [gc][pl][e][f], Zp f32 ----------
__global__ __launch_bounds__(256)
void prefix_scan(float* __restrict__ sbuf, const float* __restrict__ zbuf,
                 u16* __restrict__ SpT, float* __restrict__ Zp,
                 float* __restrict__ outZ, float* __restrict__ outS)
{
    __shared__ float trans[64 * 68];
    const int bh = blockIdx.x >> 2, f0 = (blockIdx.x & 3) * 64;
    const int tid = threadIdx.x;
    float run[16];
    #pragma unroll
    for (int i = 0; i < 16; i++) run[i] = 0.f;
    float zrun = 0.f;
    for (int c = 0; c < 32; c++) {
        const int gc = bh * 32 + c;
        const float* base = sbuf + (size_t)gc * 16384 + f0 * 64;
        float v[16];
        #pragma unroll
        for (int i = 0; i < 16; i++) v[i] = base[tid + i * 256];
        #pragma unroll
        for (int i = 0; i < 16; i++) {
            int idx = tid + i * 256;
            trans[(idx & 63) * 68 + (idx >> 6)] = run[i];
        }
        float zv = 0.f;
        if (tid < 64) zv = zbuf[(size_t)gc * 256 + f0 + tid];
        __syncthreads();
        {
            int e = tid >> 2, fl = (tid & 3) * 16;
            float* tp = &trans[e * 68 + fl];
            alignas(16) u16 hbuf[16], lbuf[16];
            #pragma unroll
            for (int q = 0; q < 16; q++) {
                float vv = tp[q];
                u16 hh = f2bf(vv);
                hbuf[q] = hh;
                lbuf[q] = f2bf(vv - bf2f(hh));
            }
            u16* dh = SpT + (size_t)gc * 32768 + e * 256 + f0 + fl;
            *(uint4*)dh = *(uint4*)&hbuf[0];
            *(uint4*)(dh + 8) = *(uint4*)&hbuf[8];
            u16* dl = dh + 16384;
            *(uint4*)dl = *(uint4*)&lbuf[0];
            *(uint4*)(dl + 8) = *(uint4*)&lbuf[8];
        }
        if (tid < 64) { Zp[(size_t)gc * 256 + f0 + tid] = zrun; zrun += zv; }
        #pragma unroll
        for (int i = 0; i < 16; i++) run[i] += v[i];
        __syncthreads();
    }
    #pragma unroll
    for (int i = 0; i < 16; i++)
        outS[(size_t)bh * 16384 + f0 * 64 + tid + i * 256] = run[i];
    if (tid < 64) outZ[bh * 256 + f0 + tid] = zrun;
}

// ---------- Pass C: aout = Dinv*(Q@Sprev + tril(QK^T)@V), all MFMA ----------
__global__ __launch_bounds__(256)
void chunk_out_mfma(const u16* __restrict__ phiQ, const u16* __restrict__ phiK,
                    const u16* __restrict__ Vt, const u16* __restrict__ SpT,
                    const float* __restrict__ Zp, float* __restrict__ aout)
{
    extern __shared__ char sm[];
    char* bufQ = sm;             // [128][64] swz Q-slab ; later V_lo [64][128] swz
    char* bufK = sm + 16384;     // [128][64] swz K-slab ; later V_hi [64][128] swz
    char* bufA = sm + 32768;     // f0 loop: Sp_hi [64][64] @+0, Sp_lo @+8192 ; after: A [128][128] swz
    float* Dl = (float*)(sm + 65536);    // [128]
    float* Zl = (float*)(sm + 66048);    // [64]
    const int gc = blockIdx.x, c = gc & 31, bh = gc >> 5, b = bh >> 3, h = bh & 7;
    const int row0 = b * 4096 + c * 128;
    const u16* Qg = phiQ + (size_t)row0 * 2048 + h * 256;
    const u16* Kg = phiK + (size_t)row0 * 2048 + h * 256;
    const u16* Vg = Vt + (size_t)gc * 16384;
    const u16* Sg = SpT + (size_t)gc * 32768;
    const float* Zg = Zp + (size_t)gc * 256;
    const int tid = threadIdx.x, lane = tid & 63, wave = tid >> 6;
    const int fr = lane & 15, fk = (lane >> 4) * 8;
    const int dr = tid >> 1, dc = (tid & 1) * 32;

    f32x4 acc2[2][8] = {};   // QK^T: rows wave*32.., 128 cols
    f32x4 acc1[2][4] = {};   // out:  rows wave*32.., 64 e
    float dotZ = 0.f, sumQ = 0.f;

    for (int f0 = 0; f0 < 256; f0 += 64) {
        float4 vq[4], vk[4], vsh[2], vsl[2];
        #pragma unroll
        for (int j = 0; j < 4; j++) {
            int ci = tid + j * 256; int r = ci >> 3, cc = (ci & 7) * 8;
            vq[j] = *(const float4*)(Qg + (size_t)r * 2048 + f0 + cc);
            vk[j] = *(const float4*)(Kg + (size_t)r * 2048 + f0 + cc);
        }
        #pragma unroll
        for (int j = 0; j < 2; j++) {
            int ci = tid + j * 256; int e = ci >> 3, cc = (ci & 7) * 8;
            vsh[j] = *(const float4*)(Sg + (size_t)e * 256 + f0 + cc);
            vsl[j] = *(const float4*)(Sg + 16384 + (size_t)e * 256 + f0 + cc);
        }
        __syncthreads();
        #pragma unroll
        for (int j = 0; j < 4; j++) {
            int ci = tid + j * 256; int r = ci >> 3, cc = (ci & 7) * 8;
            *(float4*)(bufQ + swz(r, cc, 64)) = vq[j];
            *(float4*)(bufK + swz(r, cc, 64)) = vk[j];
        }
        #pragma unroll
        for (int j = 0; j < 2; j++) {
            int ci = tid + j * 256; int e = ci >> 3, cc = (ci & 7) * 8;
            *(float4*)(bufA + swz(e, cc, 64)) = vsh[j];
            *(float4*)(bufA + 8192 + swz(e, cc, 64)) = vsl[j];
        }
        if (tid < 64) Zl[tid] = Zg[f0 + tid];
        __syncthreads();
        #pragma unroll
        for (int ks = 0; ks < 2; ks++) {
            bf16x8 af[2];
            af[0] = *(bf16x8*)(bufQ + swz(wave * 32 + fr, ks * 32 + fk, 64));
            af[1] = *(bf16x8*)(bufQ + swz(wave * 32 + 16 + fr, ks * 32 + fk, 64));
            #pragma unroll
            for (int nf = 0; nf < 8; nf++) {
                bf16x8 bv = *(bf16x8*)(bufK + swz(nf * 16 + fr, ks * 32 + fk, 64));
                acc2[0][nf] = MF(af[0], bv, acc2[0][nf]);
                acc2[1][nf] = MF(af[1], bv, acc2[1][nf]);
            }
            #pragma unroll
            for (int nf = 0; nf < 4; nf++) {
                bf16x8 bvh = *(bf16x8*)(bufA + swz(nf * 16 + fr, ks * 32 + fk, 64));
                bf16x8 bvl = *(bf16x8*)(bufA + 8192 + swz(nf * 16 + fr, ks * 32 + fk, 64));
                acc1[0][nf] = MF(af[0], bvh, acc1[0][nf]);
                acc1[1][nf] = MF(af[1], bvh, acc1[1][nf]);
                acc1[0][nf] = MF(af[0], bvl, acc1[0][nf]);
                acc1[1][nf] = MF(af[1], bvl, acc1[1][nf]);
            }
        }
        // D partials: row dr, cols dc..dc+31 of this 64-wide f-slab
        #pragma unroll
        for (int jj = 0; jj < 4; jj++) {
            bf16x8 qv = *(bf16x8*)(bufQ + swz(dr, dc + jj * 8, 64));
            f32x4 z0 = *(f32x4*)(Zl + dc + jj * 8);
            f32x4 z1 = *(f32x4*)(Zl + dc + jj * 8 + 4);
            #pragma unroll
            for (int q = 0; q < 8; q++) {
                float qf = bf2f((u16)qv[q]);
                sumQ += qf;
                dotZ += qf * (q < 4 ? z0[q] : z1[q - 4]);
            }
        }
    }
    __syncthreads();
    // stage V hi/lo (regs) + write tril(A) bf16 into bufA
    float4 vvh[4], vvl[4];
    #pragma unroll
    for (int j = 0; j < 4; j++) {
        int ci = tid + j * 256; int e = ci >> 4, cc = (ci & 15) * 8;
        vvh[j] = *(const float4*)(Vg + (size_t)e * 128 + cc);
        vvl[j] = *(const float4*)(Vg + 8192 + (size_t)e * 128 + cc);
    }
    #pragma unroll
    for (int mf = 0; mf < 2; mf++) {
        int rb = wave * 32 + mf * 16 + (lane >> 4) * 4;
        #pragma unroll
        for (int nf = 0; nf < 8; nf++) {
            int col = nf * 16 + fr;
            #pragma unroll
            for (int r = 0; r < 4; r++) {
                float v = (col <= rb + r) ? acc2[mf][nf][r] : 0.f;
                *(u16*)(bufA + swz(rb + r, col, 128)) = f2bf(v);
            }
        }
    }
    #pragma unroll
    for (int j = 0; j < 4; j++) {
        int ci = tid + j * 256; int e = ci >> 4, cc = (ci & 15) * 8;
        *(float4*)(bufK + swz(e, cc, 128)) = vvh[j];
        *(float4*)(bufQ + swz(e, cc, 128)) = vvl[j];
    }
    __syncthreads();
    // D row totals: FULL 128-col rowsum of bf16 A (2 threads/row, 64 cols each)
    {
        const int dcA = (tid & 1) * 64;
        float rs = 0.f;
        #pragma unroll
        for (int jj = 0; jj < 8; jj++) {
            bf16x8 av = *(bf16x8*)(bufA + swz(dr, dcA + jj * 8, 128));
            #pragma unroll
            for (int q = 0; q < 8; q++) rs += bf2f((u16)av[q]);
        }
        float tot = rs + dotZ + 1e-6f * sumQ;
        tot += __shfl_xor(tot, 1);
        if ((tid & 1) == 0) Dl[dr] = tot;
    }
    // phase 3: out += tril(A) @ (Vhi + Vlo)
    #pragma unroll
    for (int ks = 0; ks < 4; ks++) {
        bf16x8 af[2];
        af[0] = *(bf16x8*)(bufA + swz(wave * 32 + fr, ks * 32 + fk, 128));
        af[1] = *(bf16x8*)(bufA + swz(wave * 32 + 16 + fr, ks * 32 + fk, 128));
        #pragma unroll
        for (int nf = 0; nf < 4; nf++) {
            bf16x8 bvh = *(bf16x8*)(bufK + swz(nf * 16 + fr, ks * 32 + fk, 128));
            bf16x8 bvl = *(bf16x8*)(bufQ + swz(nf * 16 + fr, ks * 32 + fk, 128));
            acc1[0][nf] = MF(af[0], bvh, acc1[0][nf]);
            acc1[1][nf] = MF(af[1], bvh, acc1[1][nf]);
            acc1[0][nf] = MF(af[0], bvl, acc1[0][nf]);
            acc1[1][nf] = MF(af[1], bvl, acc1[1][nf]);
        }
    }
    __syncthreads();
    #pragma unroll
    for (int mf = 0; mf < 2; mf++) {
        int rb = wave * 32 + mf * 16 + (lane >> 4) * 4;
        #pragma unroll
        for (int r = 0; r < 4; r++) {
            float dinv = 1.f / Dl[rb + r];
            #pragma unroll
            for (int nf = 0; nf < 4; nf++)
                aout[(size_t)(row0 + rb + r) * 512 + h * 64 + nf * 16 + fr]
                    = acc1[mf][nf][r] * dinv;
        }
    }
}

extern "C" void kernel_launch(void* const* d_in, const int* in_sizes, int n_in,
                              void* d_out, int out_size, void* d_ws, size_t ws_size,
                              hipStream_t stream)
{
    const float* x    = (const float*)d_in[0];
    const float* Wq   = (const float*)d_in[1];
    const float* Wk   = (const float*)d_in[2];
    const float* Wv   = (const float*)d_in[3];
    const float* Wo   = (const float*)d_in[4];
    const float* bo   = (const float*)d_in[5];
    const float* proj = (const float*)d_in[6];
    float* out = (float*)d_out;
    float* ws = (float*)d_ws;

    // layout (floats), total 66,871,360 f (same as round 3)
    float* qkv  = ws;                           // [8192][1536] f32 (q|k|v)
    float* dd   = ws + 12582912;                // [16384][2048] f32 (q rows | k rows)
    //   dd region reuse after feat_fin:
    u16*   phiKT = (u16*)dd;                            // 512*32768 u16 (8.39M f)
    u16*   Vtb   = (u16*)(ws + 20971520);               // 512*2*64*128 u16 (4.19M f)
    float* sbuf  = ws + 25165824;                       // 8.39M f
    u16*   SpT   = (u16*)(ws + 33554432);               // 512*2*64*256 u16 (8.39M f)
    float* aout  = ws + 41943040;                       // [8192][512] f32 (4.19M f)
    float* zbuf = ws + 46137344;                // 128K
    float* Zp   = ws + 46268416;                // 128K
    u32*   gmax = (u32*)(ws + 46399488);
    u16* xs  = (u16*)(ws + 46399552);           // [8192][1536] u16 (6.29M f)
    u16* qs  = (u16*)(ws + 52691008);           // [8192][1536] u16 (q split)
    u16* ks_ = (u16*)(ws + 58982464);           // [8192][1536] u16 (k split, contiguous)
    u16* phi = (u16*)(ws + 46399552);           // [16384][2048] u16 overlays xs/qs/ks (dead)
    u16* aouts = (u16*)(ws + 46399552);         // overlays phi (dead after chunk_out)
    u16* Wqkvs = (u16*)(ws + 65273920);         // [1536][1536] u16
    u16* Wos   = (u16*)(ws + 66453568);         // [512][1536] u16
    u16* projs = (u16*)(ws + 66846784);         // [256][192] u16
    (void)ks_;

    float* outO = out;                 // [2,4096,512]
    float* outZ = out + 4194304;       // [2,8,256]
    float* outS = out + 4198400;       // [2,8,256,64]

    dim3 blk(256);

    // split converts
    conv_split<false><<<2048, blk, 0, stream>>>(x, xs, 512, 1048576L, 1.f);
    conv_split<true ><<<256, blk, 0, stream>>>(Wq, Wqkvs, 512, 65536L, 1.f);
    conv_split<true ><<<256, blk, 0, stream>>>(Wk, Wqkvs + 786432, 512, 65536L, 1.f);
    conv_split<true ><<<256, blk, 0, stream>>>(Wv, Wqkvs + 1572864, 512, 65536L, 1.f);
    conv_split<true ><<<256, blk, 0, stream>>>(Wo, Wos, 512, 65536L, 1.f);
    conv_split<true ><<<16, blk, 0, stream>>>(proj, projs, 64, 4096L, 1.f);
    // fused QKV projection: qkv = x @ [Wq|Wk|Wv]^T   (M=8192, N=1536, K=1536 split)
    gemm_mfma<false><<<dim3(64, 12, 1), blk, 0, stream>>>(
        xs, 1536, 0, Wqkvs, 1536, 0, qkv, 1536, 0, nullptr, 1536, 1.f, nullptr, 0);
    // per-head split converts of q,k (dn folded), one launch
    conv_qk<<<2048, blk, 0, stream>>>(qkv, qs);
    hipMemsetAsync(gmax, 0, 4, stream);
    // batched dd = (dn*qk) @ proj^T  (M=16384: q rows | k rows; z=head)
    // fused global-max over k half (blockIdx.x >= 64)
    gemm_mfma<false><<<dim3(128, 2, 8), blk, 0, stream>>>(
        qs, 1536, 192, projs, 192, 0, dd, 2048, 256, nullptr, 192, 1.f, gmax, 64);
    // fused feature maps -> bf16 phi [16384][2048]
    feat_fin<<<32768, blk, 0, stream>>>(dd, qkv, gmax, phi);
    // transposes
    transpose_k<<<512, blk, 0, stream>>>(phi + (size_t)8192 * 2048, phiKT);
    transpose_v<<<512, blk, 0, stream>>>(qkv + 1024, Vtb, 1536);
    // chunked linear attention
    chunk_sums_mfma<<<512, blk, 0, stream>>>(phiKT, Vtb, sbuf, zbuf);
    prefix_scan<<<64, blk, 0, stream>>>(sbuf, zbuf, SpT, Zp, outZ, outS);
    hipFuncSetAttribute((const void*)chunk_out_mfma,
                        hipFuncAttributeMaxDynamicSharedMemorySize, 66304);
    chunk_out_mfma<<<512, blk, 66304, stream>>>(phi, phi + (size_t)8192 * 2048,
                                                Vtb, SpT, Zp, aout);
    // final projection
    conv_split<false><<<2048, blk, 0, stream>>>(aout, aouts, 512, 1048576L, 1.f);
    gemm_mfma<true><<<dim3(64, 4, 1), blk, 0, stream>>>(
        aouts, 1536, 0, Wos, 1536, 0, outO, 512, 0, bo, 1536, 1.f, nullptr, 0);
}

// Round 6
// 549.625 us; speedup vs baseline: 2.0852x; 1.0244x over previous
//
#include <hip/hip_runtime.h>

#define NH 8
#define DH 64
#define FF 256
#define CH 128

typedef unsigned short u16;
typedef unsigned int u32;
typedef __attribute__((ext_vector_type(8))) short bf16x8;
typedef __attribute__((ext_vector_type(4))) float f32x4;

__device__ __forceinline__ u16 f2bf(float f) {
    u32 u = __float_as_uint(f);
    return (u16)((u + 0x7fffu + ((u >> 16) & 1u)) >> 16);
}
__device__ __forceinline__ float bf2f(u16 h) { return __uint_as_float(((u32)h) << 16); }
__device__ __forceinline__ u32 pk(u16 a, u16 b) { return (u32)a | ((u32)b << 16); }
// XOR-swizzled byte offset for bf16 LDS tiles (ld = row elems, mult of 64)
__device__ __forceinline__ int swz(int row, int col, int ld) {
    return ((row * ld + col) * 2) ^ ((row & 7) << 4);
}
__device__ __forceinline__ f32x4 MF(bf16x8 a, bf16x8 b, f32x4 c) {
    return __builtin_amdgcn_mfma_f32_16x16x32_bf16(a, b, c, 0, 0, 0);
}
__device__ __forceinline__ float wave_max(float v) {
    #pragma unroll
    for (int o = 32; o; o >>= 1) v = fmaxf(v, __shfl_xor(v, o));
    return v;
}

// ---------- split-bf16 convert: A:[hi|hi|lo]  B:[hi|lo|hi] ----------
template<bool ISB>
__global__ __launch_bounds__(256)
void conv_split(const float* __restrict__ src, u16* __restrict__ dst,
                int K, long total4, float scale)
{
    const int K4 = K >> 2;
    for (long i = (long)blockIdx.x * 256 + threadIdx.x; i < total4;
         i += (long)gridDim.x * 256) {
        long row = i / K4;
        int c = (int)(i - row * K4) * 4;
        float4 v = ((const float4*)src)[i];
        float a0 = v.x * scale, a1 = v.y * scale, a2 = v.z * scale, a3 = v.w * scale;
        u16 h0 = f2bf(a0), h1 = f2bf(a1), h2 = f2bf(a2), h3 = f2bf(a3);
        u16 l0 = f2bf(a0 - bf2f(h0)), l1 = f2bf(a1 - bf2f(h1));
        u16 l2 = f2bf(a2 - bf2f(h2)), l3 = f2bf(a3 - bf2f(h3));
        uint2 hh; hh.x = pk(h0, h1); hh.y = pk(h2, h3);
        uint2 ll; ll.x = pk(l0, l1); ll.y = pk(l2, l3);
        u16* d = dst + row * (3L * K) + c;
        *(uint2*)d = hh;
        *(uint2*)(d + (ISB ? 2 * K : K)) = hh;
        *(uint2*)(d + (ISB ? K : 2 * K)) = ll;
    }
}

// ---------- q,k head-slice split convert (+ fused diag = 0.5*||dn*q||^2) ----------
__global__ __launch_bounds__(256)
void conv_qk(const float* __restrict__ qkv, u16* __restrict__ qs,
             float* __restrict__ diagb)
{
    const float dn = 0.35355339059327373f; // 64^-0.25
    for (long i = (long)blockIdx.x * 256 + threadIdx.x; i < 2097152L;
         i += (long)gridDim.x * 256) {
        int which = i >= 1048576L;               // 0=q, 1=k
        long t = i - (long)which * 1048576L;     // r*128 + h*16 + jq
        int r = (int)(t >> 7);
        int h = ((int)t >> 4) & 7;
        int jq = ((int)t & 15) * 4;
        const float* s = qkv + (size_t)r * 1536 + which * 512 + h * 64 + jq;
        float4 v = *(const float4*)s;
        float a0 = v.x * dn, a1 = v.y * dn, a2 = v.z * dn, a3 = v.w * dn;
        float ss = a0*a0 + a1*a1 + a2*a2 + a3*a3;
        #pragma unroll
        for (int o = 1; o < 16; o <<= 1) ss += __shfl_xor(ss, o);
        if ((threadIdx.x & 15) == 0)
            diagb[(size_t)which * 65536 + r * 8 + h] = 0.5f * ss;
        u16 h0 = f2bf(a0), h1 = f2bf(a1), h2 = f2bf(a2), h3 = f2bf(a3);
        u16 l0 = f2bf(a0 - bf2f(h0)), l1 = f2bf(a1 - bf2f(h1));
        u16 l2 = f2bf(a2 - bf2f(h2)), l3 = f2bf(a3 - bf2f(h3));
        uint2 hh; hh.x = pk(h0, h1); hh.y = pk(h2, h3);
        uint2 ll; ll.x = pk(l0, l1); ll.y = pk(l2, l3);
        u16* d = qs + (size_t)which * 12582912 + (size_t)r * 1536 + h * 192 + jq;
        *(uint2*)d = hh;
        *(uint2*)(d + 64) = hh;
        *(uint2*)(d + 128) = ll;
    }
}

// ---------- bf16 MFMA NT GEMM: C = scale * A @ B^T (+bias). 128x128 tile, BK=64 ----------
template<bool HAS_BIAS>
__global__ __launch_bounds__(256, 2)
void gemm_mfma(const u16* __restrict__ A, int lda, int zA,
               const u16* __restrict__ B, int ldb, int zB,
               float* __restrict__ C, int ldc, int zC,
               const float* __restrict__ bias, int K, float scale)
{
    __shared__ char smem[32768];
    char* As = smem; char* Bs = smem + 16384;
    A += (size_t)blockIdx.z * zA; B += (size_t)blockIdx.z * zB; C += (size_t)blockIdx.z * zC;
    const int m0 = blockIdx.x * 128, n0 = blockIdx.y * 128;
    const int tid = threadIdx.x, lane = tid & 63, wave = tid >> 6;
    const int wm = (wave >> 1) * 64, wn = (wave & 1) * 64;
    const int fr = lane & 15, fk = (lane >> 4) * 8;
    f32x4 acc[4][4] = {};
    for (int k0 = 0; k0 < K; k0 += 64) {
        float4 va[4], vb[4];
        #pragma unroll
        for (int j = 0; j < 4; j++) {
            int ci = tid + j * 256; int r = ci >> 3, cc = (ci & 7) * 8;
            va[j] = *(const float4*)(A + (size_t)(m0 + r) * lda + k0 + cc);
            vb[j] = *(const float4*)(B + (size_t)(n0 + r) * ldb + k0 + cc);
        }
        __syncthreads();
        #pragma unroll
        for (int j = 0; j < 4; j++) {
            int ci = tid + j * 256; int r = ci >> 3, cc = (ci & 7) * 8;
            *(float4*)(As + swz(r, cc, 64)) = va[j];
            *(float4*)(Bs + swz(r, cc, 64)) = vb[j];
        }
        __syncthreads();
        #pragma unroll
        for (int ks = 0; ks < 2; ks++) {
            bf16x8 af[4], bfv[4];
            #pragma unroll
            for (int mf = 0; mf < 4; mf++)
                af[mf] = *(bf16x8*)(As + swz(wm + mf * 16 + fr, ks * 32 + fk, 64));
            #pragma unroll
            for (int nf = 0; nf < 4; nf++)
                bfv[nf] = *(bf16x8*)(Bs + swz(wn + nf * 16 + fr, ks * 32 + fk, 64));
            #pragma unroll
            for (int mf = 0; mf < 4; mf++)
                #pragma unroll
                for (int nf = 0; nf < 4; nf++)
                    acc[mf][nf] = MF(af[mf], bfv[nf], acc[mf][nf]);
        }
    }
    #pragma unroll
    for (int mf = 0; mf < 4; mf++) {
        int rb = m0 + wm + mf * 16 + (lane >> 4) * 4;
        #pragma unroll
        for (int nf = 0; nf < 4; nf++) {
            int col = n0 + wn + nf * 16 + fr;
            float bv = HAS_BIAS ? bias[col] : 0.f;
            #pragma unroll
            for (int r = 0; r < 4; r++)
                C[(size_t)(rb + r) * ldc + col] = scale * acc[mf][nf][r] + bv;
        }
    }
}

// ---------- dd GEMM, 128 rows x 256 features per head, fused feature map ----------
// MODE 0: k max-only (no stores, blockmax -> atomic)
// MODE 1: q fused feat (per-row max) -> phi bf16 row-major
// MODE 2: k fused feat (global max) -> phi bf16 row-major
template<int MODE>
__global__ __launch_bounds__(256, 2)
void dd_gemm(const u16* __restrict__ A, const u16* __restrict__ Bp,
             const float* __restrict__ diagb, u32* __restrict__ gmax,
             u16* __restrict__ phi)
{
    __shared__ char sm_[51712];
    char* As = sm_;                       // [128][64] u16 swz (16KB)
    char* Bs = sm_ + 16384;               // [256][64] u16 swz (32KB)
    float* red  = (float*)(sm_ + 49152);  // [128][4] rowmax (Q) / [4] blockmax (Kmax)
    float* srow = (float*)(sm_ + 51200);  // [128] diag+m
    const int h = blockIdx.z, m0 = blockIdx.x * 128;
    const u16* Ag = A + (size_t)m0 * 1536 + h * 192;
    const int tid = threadIdx.x, lane = tid & 63, wave = tid >> 6;
    const int wn = wave * 64;
    const int fr = lane & 15, fk = (lane >> 4) * 8;
    f32x4 acc[8][4] = {};
    for (int k0 = 0; k0 < 192; k0 += 64) {
        float4 va[4], vb[8];
        #pragma unroll
        for (int j = 0; j < 4; j++) {
            int ci = tid + j * 256; int r = ci >> 3, cc = (ci & 7) * 8;
            va[j] = *(const float4*)(Ag + (size_t)r * 1536 + k0 + cc);
        }
        #pragma unroll
        for (int j = 0; j < 8; j++) {
            int ci = tid + j * 256; int r = ci >> 3, cc = (ci & 7) * 8;
            vb[j] = *(const float4*)(Bp + (size_t)r * 192 + k0 + cc);
        }
        __syncthreads();
        #pragma unroll
        for (int j = 0; j < 4; j++) {
            int ci = tid + j * 256; int r = ci >> 3, cc = (ci & 7) * 8;
            *(float4*)(As + swz(r, cc, 64)) = va[j];
        }
        #pragma unroll
        for (int j = 0; j < 8; j++) {
            int ci = tid + j * 256; int r = ci >> 3, cc = (ci & 7) * 8;
            *(float4*)(Bs + swz(r, cc, 64)) = vb[j];
        }
        __syncthreads();
        #pragma unroll
        for (int ks = 0; ks < 2; ks++) {
            bf16x8 af[8], bf4[4];
            #pragma unroll
            for (int mf = 0; mf < 8; mf++)
                af[mf] = *(bf16x8*)(As + swz(mf * 16 + fr, ks * 32 + fk, 64));
            #pragma unroll
            for (int nf = 0; nf < 4; nf++)
                bf4[nf] = *(bf16x8*)(Bs + swz(wn + nf * 16 + fr, ks * 32 + fk, 64));
            #pragma unroll
            for (int mf = 0; mf < 8; mf++)
                #pragma unroll
                for (int nf = 0; nf < 4; nf++)
                    acc[mf][nf] = MF(af[mf], bf4[nf], acc[mf][nf]);
        }
    }

    if constexpr (MODE == 0) {
        float mx = -1e30f;
        #pragma unroll
        for (int mf = 0; mf < 8; mf++)
            #pragma unroll
            for (int nf = 0; nf < 4; nf++)
                #pragma unroll
                for (int r = 0; r < 4; r++) mx = fmaxf(mx, acc[mf][nf][r]);
        mx = wave_max(mx);
        __syncthreads();
        if (lane == 0) red[wave] = mx;
        __syncthreads();
        if (tid == 0) {
            float m4 = fmaxf(fmaxf(red[0], red[1]), fmaxf(red[2], red[3]));
            u32 u = __float_as_uint(m4);
            u32 key = (u & 0x80000000u) ? ~u : (u | 0x80000000u);
            atomicMax(gmax, key);
        }
        return;
    }

    if constexpr (MODE == 1) {
        // per-row max over the wave's 64 cols, then cross-wave via LDS
        float rm[8][4];
        #pragma unroll
        for (int mf = 0; mf < 8; mf++)
            #pragma unroll
            for (int r = 0; r < 4; r++) {
                float m = acc[mf][0][r];
                m = fmaxf(m, acc[mf][1][r]);
                m = fmaxf(m, acc[mf][2][r]);
                m = fmaxf(m, acc[mf][3][r]);
                #pragma unroll
                for (int o = 1; o < 16; o <<= 1) m = fmaxf(m, __shfl_xor(m, o));
                rm[mf][r] = m;
            }
        __syncthreads();
        if ((lane & 15) == 0) {
            #pragma unroll
            for (int mf = 0; mf < 8; mf++)
                #pragma unroll
                for (int r = 0; r < 4; r++)
                    red[(mf * 16 + (lane >> 4) * 4 + r) * 4 + wave] = rm[mf][r];
        }
        __syncthreads();
        if (tid < 128) {
            float m4 = fmaxf(fmaxf(red[tid * 4], red[tid * 4 + 1]),
                             fmaxf(red[tid * 4 + 2], red[tid * 4 + 3]));
            srow[tid] = m4 + diagb[(size_t)(m0 + tid) * 8 + h];
        }
        __syncthreads();
        #pragma unroll
        for (int mf = 0; mf < 8; mf++)
            #pragma unroll
            for (int r = 0; r < 4; r++) {
                int row = mf * 16 + (lane >> 4) * 4 + r;
                float s = srow[row];
                #pragma unroll
                for (int nf = 0; nf < 4; nf++) {
                    float v = 0.0625f * (expf(acc[mf][nf][r] - s) + 1e-4f);
                    phi[(size_t)(m0 + row) * 2048 + h * 256 + wn + nf * 16 + fr] = f2bf(v);
                }
            }
        return;
    }

    if constexpr (MODE == 2) {
        u32 key = *gmax;
        u32 ub = (key & 0x80000000u) ? (key & 0x7fffffffu) : ~key;
        float mg = __uint_as_float(ub);
        if (tid < 128)
            srow[tid] = mg + diagb[65536 + (size_t)(m0 + tid) * 8 + h];
        __syncthreads();
        #pragma unroll
        for (int mf = 0; mf < 8; mf++)
            #pragma unroll
            for (int r = 0; r < 4; r++) {
                int row = mf * 16 + (lane >> 4) * 4 + r;
                float s = srow[row];
                #pragma unroll
                for (int nf = 0; nf < 4; nf++) {
                    float v = 0.0625f * (expf(acc[mf][nf][r] - s) + 1e-4f);
                    phi[(size_t)(m0 + row) * 2048 + h * 256 + wn + nf * 16 + fr] = f2bf(v);
                }
            }
        return;
    }
}

// ---------- transpose phiK per chunk -> phiKT[gc][f=256][r=128]  (round-4 proven) ----------
__global__ __launch_bounds__(256)
void transpose_k(const u16* __restrict__ phiK, u16* __restrict__ phiKT)
{
    __shared__ u16 tr[64 * 136];
    const int gc = blockIdx.x, c = gc & 31, bh = gc >> 5, b = bh >> 3, h = bh & 7;
    const int row0 = b * 4096 + c * 128;
    const u16* src = phiK + (size_t)row0 * 2048 + h * 256;
    u16* dst = phiKT + (size_t)gc * 32768;
    const int tid = threadIdx.x;
    for (int f0 = 0; f0 < 256; f0 += 64) {
        #pragma unroll
        for (int j = 0; j < 4; j++) {
            int ci = tid + j * 256; int r = ci >> 3, ff = (ci & 7) * 8;
            bf16x8 w = *(const bf16x8*)(src + (size_t)r * 2048 + f0 + ff);
            #pragma unroll
            for (int q = 0; q < 8; q++) tr[(ff + q) * 136 + r] = (u16)w[q];
        }
        __syncthreads();
        {
            int f = tid >> 2, r0 = (tid & 3) * 32;
            uint4 a0 = *(uint4*)&tr[f * 136 + r0];
            uint4 a1 = *(uint4*)&tr[f * 136 + r0 + 8];
            uint4 a2 = *(uint4*)&tr[f * 136 + r0 + 16];
            uint4 a3 = *(uint4*)&tr[f * 136 + r0 + 24];
            u16* dp = dst + (size_t)(f0 + f) * 128 + r0;
            *(uint4*)dp = a0; *(uint4*)(dp + 8) = a1;
            *(uint4*)(dp + 16) = a2; *(uint4*)(dp + 24) = a3;
        }
        __syncthreads();
    }
}

// ---------- transpose v per chunk -> Vt[gc][plane hi/lo][e=64][r=128] bf16 ----------
__global__ __launch_bounds__(256)
void transpose_v(const float* __restrict__ vsrc, u16* __restrict__ Vt, int srcLd)
{
    __shared__ u16 trh[64 * 136];
    __shared__ u16 trl[64 * 136];
    const int gc = blockIdx.x, c = gc & 31, bh = gc >> 5, b = bh >> 3, h = bh & 7;
    const int row0 = b * 4096 + c * 128;
    const float* src = vsrc + (size_t)row0 * srcLd + h * 64;
    u16* dst = Vt + (size_t)gc * 16384;
    const int tid = threadIdx.x;
    #pragma unroll
    for (int j = 0; j < 8; j++) {
        int ci = tid + j * 256; int r = ci >> 4, e = (ci & 15) * 4;
        float4 v = *(const float4*)(src + (size_t)r * srcLd + e);
        float vf[4] = {v.x, v.y, v.z, v.w};
        #pragma unroll
        for (int q = 0; q < 4; q++) {
            u16 hh = f2bf(vf[q]);
            trh[(e + q) * 136 + r] = hh;
            trl[(e + q) * 136 + r] = f2bf(vf[q] - bf2f(hh));
        }
    }
    __syncthreads();
    int e = tid >> 2, r0 = (tid & 3) * 32;
    #pragma unroll
    for (int q = 0; q < 4; q++) {
        uint4 a = *(uint4*)&trh[e * 136 + r0 + q * 8];
        *(uint4*)(dst + (size_t)e * 128 + r0 + q * 8) = a;
    }
    #pragma unroll
    for (int q = 0; q < 4; q++) {
        uint4 a = *(uint4*)&trl[e * 136 + r0 + q * 8];
        *(uint4*)(dst + 8192 + (size_t)e * 128 + r0 + q * 8) = a;
    }
}

// ---------- Pass A: S = K^T (Vhi+Vlo), Z = colsum(K) ----------
__global__ __launch_bounds__(256)
void chunk_sums_mfma(const u16* __restrict__ phiKT, const u16* __restrict__ Vt,
                     float* __restrict__ sbuf, float* __restrict__ zbuf)
{
    __shared__ char smem[49152];
    char* bufA = smem;            // [256 f][64 r] swz
    char* bufBh = smem + 32768;   // [64 e][64 r] swz
    char* bufBl = smem + 40960;
    const int gc = blockIdx.x;
    const u16* Ag = phiKT + (size_t)gc * 32768;
    const u16* Bg = Vt + (size_t)gc * 16384;
    const int tid = threadIdx.x, lane = tid & 63, wave = tid >> 6;
    const int fr = lane & 15, fk = (lane >> 4) * 8;
    {
        float z = 0.f;
        const u16* zp = Ag + (size_t)tid * 128;
        #pragma unroll
        for (int j = 0; j < 16; j++) {
            bf16x8 w = *(const bf16x8*)(zp + j * 8);
            #pragma unroll
            for (int q = 0; q < 8; q++) z += bf2f((u16)w[q]);
        }
        zbuf[(size_t)gc * 256 + tid] = z;
    }
    f32x4 acc[4][4] = {};
    for (int kh = 0; kh < 2; kh++) {
        float4 va[8], vbh[2], vbl[2];
        #pragma unroll
        for (int j = 0; j < 8; j++) {
            int ci = tid + j * 256; int f = ci >> 3, rr = (ci & 7) * 8;
            va[j] = *(const float4*)(Ag + (size_t)f * 128 + kh * 64 + rr);
        }
        #pragma unroll
        for (int j = 0; j < 2; j++) {
            int ci = tid + j * 256; int e = ci >> 3, rr = (ci & 7) * 8;
            vbh[j] = *(const float4*)(Bg + (size_t)e * 128 + kh * 64 + rr);
            vbl[j] = *(const float4*)(Bg + 8192 + (size_t)e * 128 + kh * 64 + rr);
        }
        __syncthreads();
        #pragma unroll
        for (int j = 0; j < 8; j++) {
            int ci = tid + j * 256; int f = ci >> 3, rr = (ci & 7) * 8;
            *(float4*)(bufA + swz(f, rr, 64)) = va[j];
        }
        #pragma unroll
        for (int j = 0; j < 2; j++) {
            int ci = tid + j * 256; int e = ci >> 3, rr = (ci & 7) * 8;
            *(float4*)(bufBh + swz(e, rr, 64)) = vbh[j];
            *(float4*)(bufBl + swz(e, rr, 64)) = vbl[j];
        }
        __syncthreads();
        #pragma unroll
        for (int ks = 0; ks < 2; ks++) {
            bf16x8 af[4], bh4[4], bl4[4];
            #pragma unroll
            for (int mf = 0; mf < 4; mf++)
                af[mf] = *(bf16x8*)(bufA + swz(wave * 64 + mf * 16 + fr, ks * 32 + fk, 64));
            #pragma unroll
            for (int nf = 0; nf < 4; nf++) {
                bh4[nf] = *(bf16x8*)(bufBh + swz(nf * 16 + fr, ks * 32 + fk, 64));
                bl4[nf] = *(bf16x8*)(bufBl + swz(nf * 16 + fr, ks * 32 + fk, 64));
            }
            #pragma unroll
            for (int mf = 0; mf < 4; mf++)
                #pragma unroll
                for (int nf = 0; nf < 4; nf++) {
                    acc[mf][nf] = MF(af[mf], bh4[nf], acc[mf][nf]);
                    acc[mf][nf] = MF(af[mf], bl4[nf], acc[mf][nf]);
                }
        }
        __syncthreads();
    }
    #pragma unroll
    for (int mf = 0; mf < 4; mf++) {
        int fb = wave * 64 + mf * 16 + (lane >> 4) * 4;
        #pragma unroll
        for (int nf = 0; nf < 4; nf++) {
            int e = nf * 16 + fr;
            #pragma unroll
            for (int r = 0; r < 4; r++)
                sbuf[(size_t)gc * 16384 + (size_t)(fb + r) * 64 + e] = acc[mf][nf][r];
        }
    }
}

// ---------- Pass B: exclusive prefix; SpT hi/lo bf16 [gc][pl][e][f], Zp f32 (round-4 proven) ----------
__global__ __launch_bounds__(256)
void prefix_scan(const float* __restrict__ sbuf, const float* __restrict__ zbuf,
                 u16* __restrict__ SpT, float* __restrict__ Zp,
                 float* __restrict__ outZ, float* __restrict__ outS)
{
    __shared__ float trans[64 * 68];
    const int bh = blockIdx.x >> 2, f0 = (blockIdx.x & 3) * 64;
    const int tid = threadIdx.x;
    float run[16];
    #pragma unroll
    for (int i = 0; i < 16; i++) run[i] = 0.f;
    float zrun = 0.f;
    for (int c = 0; c < 32; c++) {
        const int gc = bh * 32 + c;
        const float* base = sbuf + (size_t)gc * 16384 + f0 * 64;
        float v[16];
        #pragma unroll
        for (int i = 0; i < 16; i++) v[i] = base[tid + i * 256];
        #pragma unroll
        for (int i = 0; i < 16; i++) {
            int idx = tid + i * 256;
            trans[(idx & 63) * 68 + (idx >> 6)] = run[i];
        }
        float zv = 0.f;
        if (tid < 64) zv = zbuf[(size_t)gc * 256 + f0 + tid];
        __syncthreads();
        {
            int e = tid >> 2, fl = (tid & 3) * 16;
            float* tp = &trans[e * 68 + fl];
            alignas(16) u16 hbuf[16], lbuf[16];
            #pragma unroll
            for (int q = 0; q < 16; q++) {
                float vv = tp[q];
                u16 hh = f2bf(vv);
                hbuf[q] = hh;
                lbuf[q] = f2bf(vv - bf2f(hh));
            }
            u16* dh = SpT + (size_t)gc * 32768 + e * 256 + f0 + fl;
            *(uint4*)dh = *(uint4*)&hbuf[0];
            *(uint4*)(dh + 8) = *(uint4*)&hbuf[8];
            u16* dl = dh + 16384;
            *(uint4*)dl = *(uint4*)&lbuf[0];
            *(uint4*)(dl + 8) = *(uint4*)&lbuf[8];
        }
        if (tid < 64) { Zp[(size_t)gc * 256 + f0 + tid] = zrun; zrun += zv; }
        #pragma unroll
        for (int i = 0; i < 16; i++) run[i] += v[i];
        __syncthreads();
    }
    #pragma unroll
    for (int i = 0; i < 16; i++)
        outS[(size_t)bh * 16384 + f0 * 64 + tid + i * 256] = run[i];
    if (tid < 64) outZ[bh * 256 + f0 + tid] = zrun;
}

// ---------- Pass C: aout = Dinv*(Q@Sprev + tril(QK^T)@V), all MFMA ----------
__global__ __launch_bounds__(256)
void chunk_out_mfma(const u16* __restrict__ phiQ, const u16* __restrict__ phiK,
                    const u16* __restrict__ Vt, const u16* __restrict__ SpT,
                    const float* __restrict__ Zp, float* __restrict__ aout)
{
    extern __shared__ char sm[];
    char* bufQ = sm;             // [128][64] swz Q-slab ; later V_lo [64][128] swz
    char* bufK = sm + 16384;     // [128][64] swz K-slab ; later V_hi [64][128] swz
    char* bufA = sm + 32768;     // f0 loop: Sp_hi @+0, Sp_lo @+8192 ; after: A [128][128] swz
    float* Dl = (float*)(sm + 65536);    // [128]
    float* Zl = (float*)(sm + 66048);    // [64]
    const int gc = blockIdx.x, c = gc & 31, bh = gc >> 5, b = bh >> 3, h = bh & 7;
    const int row0 = b * 4096 + c * 128;
    const u16* Qg = phiQ + (size_t)row0 * 2048 + h * 256;
    const u16* Kg = phiK + (size_t)row0 * 2048 + h * 256;
    const u16* Vg = Vt + (size_t)gc * 16384;
    const u16* Sg = SpT + (size_t)gc * 32768;
    const float* Zg = Zp + (size_t)gc * 256;
    const int tid = threadIdx.x, lane = tid & 63, wave = tid >> 6;
    const int fr = lane & 15, fk = (lane >> 4) * 8;
    const int dr = tid >> 1, dc = (tid & 1) * 32;

    f32x4 acc2[2][8] = {};
    f32x4 acc1[2][4] = {};
    float dotZ = 0.f, sumQ = 0.f;

    for (int f0 = 0; f0 < 256; f0 += 64) {
        float4 vq[4], vk[4], vsh[2], vsl[2];
        #pragma unroll
        for (int j = 0; j < 4; j++) {
            int ci = tid + j * 256; int r = ci >> 3, cc = (ci & 7) * 8;
            vq[j] = *(const float4*)(Qg + (size_t)r * 2048 + f0 + cc);
            vk[j] = *(const float4*)(Kg + (size_t)r * 2048 + f0 + cc);
        }
        #pragma unroll
        for (int j = 0; j < 2; j++) {
            int ci = tid + j * 256; int e = ci >> 3, cc = (ci & 7) * 8;
            vsh[j] = *(const float4*)(Sg + (size_t)e * 256 + f0 + cc);
            vsl[j] = *(const float4*)(Sg + 16384 + (size_t)e * 256 + f0 + cc);
        }
        __syncthreads();
        #pragma unroll
        for (int j = 0; j < 4; j++) {
            int ci = tid + j * 256; int r = ci >> 3, cc = (ci & 7) * 8;
            *(float4*)(bufQ + swz(r, cc, 64)) = vq[j];
            *(float4*)(bufK + swz(r, cc, 64)) = vk[j];
        }
        #pragma unroll
        for (int j = 0; j < 2; j++) {
            int ci = tid + j * 256; int e = ci >> 3, cc = (ci & 7) * 8;
            *(float4*)(bufA + swz(e, cc, 64)) = vsh[j];
            *(float4*)(bufA + 8192 + swz(e, cc, 64)) = vsl[j];
        }
        if (tid < 64) Zl[tid] = Zg[f0 + tid];
        __syncthreads();
        #pragma unroll
        for (int ks = 0; ks < 2; ks++) {
            bf16x8 af[2];
            af[0] = *(bf16x8*)(bufQ + swz(wave * 32 + fr, ks * 32 + fk, 64));
            af[1] = *(bf16x8*)(bufQ + swz(wave * 32 + 16 + fr, ks * 32 + fk, 64));
            #pragma unroll
            for (int nf = 0; nf < 8; nf++) {
                bf16x8 bv = *(bf16x8*)(bufK + swz(nf * 16 + fr, ks * 32 + fk, 64));
                acc2[0][nf] = MF(af[0], bv, acc2[0][nf]);
                acc2[1][nf] = MF(af[1], bv, acc2[1][nf]);
            }
            #pragma unroll
            for (int nf = 0; nf < 4; nf++) {
                bf16x8 bvh = *(bf16x8*)(bufA + swz(nf * 16 + fr, ks * 32 + fk, 64));
                bf16x8 bvl = *(bf16x8*)(bufA + 8192 + swz(nf * 16 + fr, ks * 32 + fk, 64));
                acc1[0][nf] = MF(af[0], bvh, acc1[0][nf]);
                acc1[1][nf] = MF(af[1], bvh, acc1[1][nf]);
                acc1[0][nf] = MF(af[0], bvl, acc1[0][nf]);
                acc1[1][nf] = MF(af[1], bvl, acc1[1][nf]);
            }
        }
        #pragma unroll
        for (int jj = 0; jj < 4; jj++) {
            bf16x8 qv = *(bf16x8*)(bufQ + swz(dr, dc + jj * 8, 64));
            f32x4 z0 = *(f32x4*)(Zl + dc + jj * 8);
            f32x4 z1 = *(f32x4*)(Zl + dc + jj * 8 + 4);
            #pragma unroll
            for (int q = 0; q < 8; q++) {
                float qf = bf2f((u16)qv[q]);
                sumQ += qf;
                dotZ += qf * (q < 4 ? z0[q] : z1[q - 4]);
            }
        }
    }
    __syncthreads();
    float4 vvh[4], vvl[4];
    #pragma unroll
    for (int j = 0; j < 4; j++) {
        int ci = tid + j * 256; int e = ci >> 4, cc = (ci & 15) * 8;
        vvh[j] = *(const float4*)(Vg + (size_t)e * 128 + cc);
        vvl[j] = *(const float4*)(Vg + 8192 + (size_t)e * 128 + cc);
    }
    #pragma unroll
    for (int mf = 0; mf < 2; mf++) {
        int rb = wave * 32 + mf * 16 + (lane >> 4) * 4;
        #pragma unroll
        for (int nf = 0; nf < 8; nf++) {
            int col = nf * 16 + fr;
            #pragma unroll
            for (int r = 0; r < 4; r++) {
                float v = (col <= rb + r) ? acc2[mf][nf][r] : 0.f;
                *(u16*)(bufA + swz(rb + r, col, 128)) = f2bf(v);
            }
        }
    }
    #pragma unroll
    for (int j = 0; j < 4; j++) {
        int ci = tid + j * 256; int e = ci >> 4, cc = (ci & 15) * 8;
        *(float4*)(bufK + swz(e, cc, 128)) = vvh[j];
        *(float4*)(bufQ + swz(e, cc, 128)) = vvl[j];
    }
    __syncthreads();
    {
        const int dcA = (tid & 1) * 64;
        float rs = 0.f;
        #pragma unroll
        for (int jj = 0; jj < 8; jj++) {
            bf16x8 av = *(bf16x8*)(bufA + swz(dr, dcA + jj * 8, 128));
            #pragma unroll
            for (int q = 0; q < 8; q++) rs += bf2f((u16)av[q]);
        }
        float tot = rs + dotZ + 1e-6f * sumQ;
        tot += __shfl_xor(tot, 1);
        if ((tid & 1) == 0) Dl[dr] = tot;
    }
    #pragma unroll
    for (int ks = 0; ks < 4; ks++) {
        bf16x8 af[2];
        af[0] = *(bf16x8*)(bufA + swz(wave * 32 + fr, ks * 32 + fk, 128));
        af[1] = *(bf16x8*)(bufA + swz(wave * 32 + 16 + fr, ks * 32 + fk, 128));
        #pragma unroll
        for (int nf = 0; nf < 4; nf++) {
            bf16x8 bvh = *(bf16x8*)(bufK + swz(nf * 16 + fr, ks * 32 + fk, 128));
            bf16x8 bvl = *(bf16x8*)(bufQ + swz(nf * 16 + fr, ks * 32 + fk, 128));
            acc1[0][nf] = MF(af[0], bvh, acc1[0][nf]);
            acc1[1][nf] = MF(af[1], bvh, acc1[1][nf]);
            acc1[0][nf] = MF(af[0], bvl, acc1[0][nf]);
            acc1[1][nf] = MF(af[1], bvl, acc1[1][nf]);
        }
    }
    __syncthreads();
    #pragma unroll
    for (int mf = 0; mf < 2; mf++) {
        int rb = wave * 32 + mf * 16 + (lane >> 4) * 4;
        #pragma unroll
        for (int r = 0; r < 4; r++) {
            float dinv = 1.f / Dl[rb + r];
            #pragma unroll
            for (int nf = 0; nf < 4; nf++)
                aout[(size_t)(row0 + rb + r) * 512 + h * 64 + nf * 16 + fr]
                    = acc1[mf][nf][r] * dinv;
        }
    }
}

extern "C" void kernel_launch(void* const* d_in, const int* in_sizes, int n_in,
                              void* d_out, int out_size, void* d_ws, size_t ws_size,
                              hipStream_t stream)
{
    const float* x    = (const float*)d_in[0];
    const float* Wq   = (const float*)d_in[1];
    const float* Wk   = (const float*)d_in[2];
    const float* Wv   = (const float*)d_in[3];
    const float* Wo   = (const float*)d_in[4];
    const float* bo   = (const float*)d_in[5];
    const float* proj = (const float*)d_in[6];
    float* out = (float*)d_out;
    float* ws = (float*)d_ws;

    // layout (float offsets), total 66,609,152 f
    float* qkv   = ws;                          // [8192][1536] f32        [0, 12582912)
    u16*   phi   = (u16*)(ws + 12582912);       // [16384][2048] u16       [12582912, 29360128)
    u16*   phiKT = (u16*)(ws + 29360128);       // 512*32768 u16           [29360128, 37748736)
    u16*   Vtb   = (u16*)(ws + 37748736);       // 512*2*64*128 u16        [37748736, 41943040)
    float* sbuf  = ws + 41943040;               // 512*16384 f32           [41943040, 50331648)
    u16*   qs    = (u16*)(ws + 41943040);       // q|k split u16, 12.58M f [41943040, 54525952)
    float* aout  = ws + 41943040;               //   overlay (written after qs/sbuf dead)
    u16*   SpT   = (u16*)(ws + 50331648);       // 512*2*64*256 u16        [50331648, 58720256)
    u16*   xs    = (u16*)(ws + 58720256);       // [8192][1536] u16        [58720256, 65011712)
    u16*   aouts = xs;                          //   overlay (xs dead after QKV gemm)
    u16*   Wqkvs = (u16*)(ws + 65011712);       // [1536][1536] u16        [65011712, 66191360)
    float* diagb = ws + 65011712;               //   overlay Wqkvs (dead after QKV gemm)
    float* zbuf  = ws + 65142784;               //   overlay Wqkvs
    float* Zp    = ws + 65273856;               //   overlay Wqkvs
    u32*   gmax  = (u32*)(ws + 65404928);       //   overlay Wqkvs
    u16*   Wos   = (u16*)(ws + 66191360);       // [512][1536] u16
    u16*   projs = (u16*)(ws + 66584576);       // [256][192] u16

    float* outO = out;                 // [2,4096,512]
    float* outZ = out + 4194304;       // [2,8,256]
    float* outS = out + 4198400;       // [2,8,256,64]

    dim3 blk(256);

    // split converts
    conv_split<false><<<2048, blk, 0, stream>>>(x, xs, 512, 1048576L, 1.f);
    conv_split<true ><<<256, blk, 0, stream>>>(Wq, Wqkvs, 512, 65536L, 1.f);
    conv_split<true ><<<256, blk, 0, stream>>>(Wk, Wqkvs + 786432, 512, 65536L, 1.f);
    conv_split<true ><<<256, blk, 0, stream>>>(Wv, Wqkvs + 1572864, 512, 65536L, 1.f);
    conv_split<true ><<<256, blk, 0, stream>>>(Wo, Wos, 512, 65536L, 1.f);
    conv_split<true ><<<16, blk, 0, stream>>>(proj, projs, 64, 4096L, 1.f);
    // fused QKV projection: qkv = x @ [Wq|Wk|Wv]^T
    gemm_mfma<false><<<dim3(64, 12, 1), blk, 0, stream>>>(
        xs, 1536, 0, Wqkvs, 1536, 0, qkv, 1536, 0, nullptr, 1536, 1.f);
    // q,k split convert + diag
    conv_qk<<<2048, blk, 0, stream>>>(qkv, qs, diagb);
    hipMemsetAsync(gmax, 0, 4, stream);
    // dd GEMMs with fused feature map (no f32 dd intermediate)
    const u16* ksplit = qs + 12582912;
    u16* phiK = phi + (size_t)8192 * 2048;
    dd_gemm<0><<<dim3(64, 1, 8), blk, 0, stream>>>(ksplit, projs, diagb, gmax, nullptr);
    dd_gemm<2><<<dim3(64, 1, 8), blk, 0, stream>>>(ksplit, projs, diagb, gmax, phiK);
    dd_gemm<1><<<dim3(64, 1, 8), blk, 0, stream>>>(qs, projs, diagb, gmax, phi);
    // transposes
    transpose_k<<<512, blk, 0, stream>>>(phiK, phiKT);
    transpose_v<<<512, blk, 0, stream>>>(qkv + 1024, Vtb, 1536);
    // chunked linear attention
    chunk_sums_mfma<<<512, blk, 0, stream>>>(phiKT, Vtb, sbuf, zbuf);
    prefix_scan<<<64, blk, 0, stream>>>(sbuf, zbuf, SpT, Zp, outZ, outS);
    hipFuncSetAttribute((const void*)chunk_out_mfma,
                        hipFuncAttributeMaxDynamicSharedMemorySize, 66304);
    chunk_out_mfma<<<512, blk, 66304, stream>>>(phi, phiK, Vtb, SpT, Zp, aout);
    // final projection
    conv_split<false><<<2048, blk, 0, stream>>>(aout, aouts, 512, 1048576L, 1.f);
    gemm_mfma<true><<<dim3(64, 4, 1), blk, 0, stream>>>(
        aouts, 1536, 0, Wos, 1536, 0, outO, 512, 0, bo, 1536, 1.f);
}